// Round 15
// baseline (467.633 us; speedup 1.0000x reference)
//
#include <hip/hip_runtime.h>
#include <stdint.h>

#define FEAT_IN 128
#define F1 32
#define F2 64
#define FJ 96
#define FH 128

#define BSH 8                  // 256 nodes per bucket
#define BNODES 256
#define NBMAX 512
#define CH 4096                // edges per scatter chunk
#define SRCBITS 17             // nN must be < 2^17
#define SRCMASK 0x1FFFFu
#define PADMAX 768             // max pad per bucket (256 nodes * 3)
#define PNPB 256               // nodes per block in poolX1
#define NP2 64                 // nodes per block in poolX2
#define GR 64                  // rows per block in gemm1v3
#define XPAD 132               // padded LDS row stride (floats) for x tile

__device__ __forceinline__ unsigned f2bf(float f) {
    unsigned u = __float_as_uint(f);
    return (u + 0x7FFFu + ((u >> 16) & 1u)) >> 16;   // RNE
}
__device__ __forceinline__ float bf2f(unsigned h) { return __uint_as_float(h << 16); }
__device__ __forceinline__ void bfacc8(float* a, uint4 v) {
    a[0] += bf2f(v.x & 0xffffu); a[1] += bf2f(v.x >> 16);
    a[2] += bf2f(v.y & 0xffffu); a[3] += bf2f(v.y >> 16);
    a[4] += bf2f(v.z & 0xffffu); a[5] += bf2f(v.z >> 16);
    a[6] += bf2f(v.w & 0xffffu); a[7] += bf2f(v.w >> 16);
}
__device__ __forceinline__ void fma4(float* acc, float s, float4 wv) {
    acc[0] = fmaf(s, wv.x, acc[0]);
    acc[1] = fmaf(s, wv.y, acc[1]);
    acc[2] = fmaf(s, wv.z, acc[2]);
    acc[3] = fmaf(s, wv.w, acc[3]);
}

// ---------- per-chunk bucket histogram -> gHistT[bucket][chunk] ----------
__global__ void histPB(const int* __restrict__ dst, int* __restrict__ gHistT,
                       int nE, int nB, int nChP) {
    __shared__ int h[NBMAX];
    int ck = blockIdx.x, t = threadIdx.x;
    int e0 = ck * CH;
    int ecnt = min(CH, nE - e0);
    if (ecnt <= 0) return;
    for (int i = t; i < nB; i += 256) h[i] = 0;
    __syncthreads();
    for (int i = t; i < ecnt; i += 256) atomicAdd(&h[dst[e0 + i] >> BSH], 1);
    __syncthreads();
    for (int b = t; b < nB; b += 256) gHistT[(size_t)b * nChP + ck] = h[b];
}

// ---------- single-block scan: per-bucket over chunks + bucket offsets ----------
__global__ void __launch_bounds__(512)
scanAll(const int* __restrict__ gHistT, int* __restrict__ gBaseT,
        int* __restrict__ boff, int nB, int nChP, int nE) {
    __shared__ int tot[512];
    __shared__ int ps[512];
    int t = threadIdx.x;
    int run = 0;
    if (t < nB) {
        const int4* hp = (const int4*)(gHistT + (size_t)t * nChP);
        int4* gp = (int4*)(gBaseT + (size_t)t * nChP);
        for (int q = 0; q < nChP / 4; ++q) {
            int4 v = hp[q];
            int4 o;
            o.x = run; run += v.x;
            o.y = run; run += v.y;
            o.z = run; run += v.z;
            o.w = run; run += v.w;
            gp[q] = o;
        }
    }
    tot[t] = (t < nB) ? run : 0;
    __syncthreads();
    ps[t] = tot[t]; __syncthreads();
    for (int off = 1; off < 512; off <<= 1) {
        int v = (t >= off) ? ps[t - off] : 0; __syncthreads();
        ps[t] += v; __syncthreads();
    }
    int excl = ps[t] - tot[t];
    if (t < nB) boff[t] = excl;
    if (t == nB - 1) boff[nB] = excl + tot[t];
    __syncthreads();
    if (t < nB) {
        int base = excl;
        int4* gp = (int4*)(gBaseT + (size_t)t * nChP);
        for (int q = 0; q < nChP / 4; ++q) {
            int4 o = gp[q];
            o.x += base; o.y += base; o.z += base; o.w += base;
            gp[q] = o;
        }
    }
}

// ---------- scatter edges into buckets (no global atomics, LDS-staged) ----------
__global__ void __launch_bounds__(256)
scatterEB2(const int* __restrict__ src, const int* __restrict__ dst,
           const int* __restrict__ gBaseT, unsigned* __restrict__ EB,
           int nE, int nB, int nChP) {
    __shared__ int lh[NBMAX], loff[NBMAX], lcur[NBMAX], gbaseL[NBMAX];
    __shared__ int ps[256];
    __shared__ unsigned stagePack[CH];
    __shared__ unsigned short stageBkt[CH];
    int ck = blockIdx.x, t = threadIdx.x;
    int e0 = ck * CH;
    int ecnt = min(CH, nE - e0);
    if (ecnt <= 0) return;
    for (int i = t; i < nB; i += 256) lh[i] = 0;
    __syncthreads();
    for (int i = t; i < ecnt; i += 256) atomicAdd(&lh[dst[e0 + i] >> BSH], 1);
    __syncthreads();
    int b0 = 2 * t, b1 = 2 * t + 1;
    int c0 = (b0 < nB) ? lh[b0] : 0;
    int c1 = (b1 < nB) ? lh[b1] : 0;
    ps[t] = c0 + c1; __syncthreads();
    for (int off = 1; off < 256; off <<= 1) {
        int v = (t >= off) ? ps[t - off] : 0; __syncthreads();
        ps[t] += v; __syncthreads();
    }
    int excl = ps[t] - (c0 + c1);
    if (b0 < nB) { loff[b0] = excl;      lcur[b0] = excl;      gbaseL[b0] = gBaseT[(size_t)b0 * nChP + ck]; }
    if (b1 < nB) { loff[b1] = excl + c0; lcur[b1] = excl + c0; gbaseL[b1] = gBaseT[(size_t)b1 * nChP + ck]; }
    __syncthreads();
    for (int i = t; i < ecnt; i += 256) {
        int d = dst[e0 + i], s = src[e0 + i];
        int bkt = d >> BSH;
        int p = atomicAdd(&lcur[bkt], 1);
        stagePack[p] = (unsigned)s | ((unsigned)(d & (BNODES - 1)) << SRCBITS);
        stageBkt[p] = (unsigned short)bkt;
    }
    __syncthreads();
    for (int i = t; i < ecnt; i += 256) {
        int bb = stageBkt[i];
        EB[gbaseL[bb] + (i - loff[bb])] = stagePack[i];
    }
}

// ---------- per-bucket counting sort -> PADDED csr (x4, sentinel nN), dinv, rs ----------
__global__ void __launch_bounds__(512)
bucketSortK(const unsigned* __restrict__ EB, const int* __restrict__ boff,
            int* __restrict__ rowptr, int* __restrict__ rowend, int* __restrict__ csrP,
            float* __restrict__ dinv, float* __restrict__ rs, int nN, int nB) {
    __shared__ int hist[BNODES];
    __shared__ int cur[BNODES];
    __shared__ int ps[256];
    int b = blockIdx.x, t = threadIdx.x;
    int beg = boff[b], end = boff[b + 1];
    if (t < 256) hist[t] = 0;
    __syncthreads();
    for (int i = beg + t; i < end; i += 512) atomicAdd(&hist[EB[i] >> SRCBITS], 1);
    __syncthreads();
    int deg = (t < 256) ? hist[t] : 0;
    int pdeg = (deg + 3) & ~3;
    if (t < 256) ps[t] = pdeg;
    __syncthreads();
    for (int off = 1; off < 256; off <<= 1) {
        int v = (t >= off && t < 256) ? ps[t - off] : 0; __syncthreads();
        if (t < 256) ps[t] += v;
        __syncthreads();
    }
    int base = ((beg + 3) & ~3) + b * PADMAX;
    int excl = 0;
    if (t < 256) {
        excl = base + ps[t] - pdeg;
        int node = (b << BSH) + t;
        if (node < nN) {
            rowptr[node] = excl;
            rowend[node] = excl + pdeg;
            dinv[node] = rsqrtf((float)deg + 1.0f);
            rs[node] = sqrtf((float)deg + 1.0f);
        }
        cur[t] = excl;
    }
    __syncthreads();
    for (int i = beg + t; i < end; i += 512) {
        unsigned v = EB[i];
        int p = atomicAdd(&cur[v >> SRCBITS], 1);
        csrP[p] = (int)(v & SRCMASK);
    }
    __syncthreads();
    if (t < 256) {
        for (int p = cur[t]; p < excl + pdeg; ++p) csrP[p] = nN;
    }
}

// ---------- gemm1 v3: 2x4 register tile, 64 rows/block ----------
__global__ void __launch_bounds__(256)
gemm1v3(const float4* __restrict__ x4, const float* __restrict__ W1,
        const float* __restrict__ dinv, unsigned* __restrict__ Gc, int nN) {
    __shared__ float Ws[FEAT_IN * F1];   // 16 KB
    __shared__ float xs[GR * XPAD];      // 33 KB
    int t = threadIdx.x;
    for (int i = t; i < FEAT_IN * F1; i += 256) Ws[i] = W1[i];
    int rb = blockIdx.x * GR;
    for (int i = t; i < GR * 32; i += 256) {
        int r = i >> 5, c = i & 31;
        int row = rb + r;
        float4 v = (row < nN) ? x4[(size_t)row * 32 + c] : make_float4(0.f, 0.f, 0.f, 0.f);
        *(float4*)(xs + r * XPAD + c * 4) = v;
    }
    __syncthreads();
    int cg = t & 7, rg = t >> 3;
    int r0 = rg * 2, r1 = r0 + 1;
    int j0 = cg * 4;
    float acc0[4] = {0.f, 0.f, 0.f, 0.f};
    float acc1[4] = {0.f, 0.f, 0.f, 0.f};
    const float4* xa4 = (const float4*)(xs + r0 * XPAD);
    const float4* xb4 = (const float4*)(xs + r1 * XPAD);
    const float4* W4 = (const float4*)Ws;
#pragma unroll 4
    for (int kc = 0; kc < 32; ++kc) {
        float4 xa = xa4[kc];
        float4 xb = xb4[kc];
        float4 w0 = W4[(4 * kc + 0) * 8 + cg];
        float4 w1 = W4[(4 * kc + 1) * 8 + cg];
        float4 w2 = W4[(4 * kc + 2) * 8 + cg];
        float4 w3 = W4[(4 * kc + 3) * 8 + cg];
        fma4(acc0, xa.x, w0); fma4(acc0, xa.y, w1);
        fma4(acc0, xa.z, w2); fma4(acc0, xa.w, w3);
        fma4(acc1, xb.x, w0); fma4(acc1, xb.y, w1);
        fma4(acc1, xb.z, w2); fma4(acc1, xb.w, w3);
    }
    int c = j0 >> 4;
    int w = (j0 & 15) >> 1;
    int row0 = rb + r0, row1 = rb + r1;
    if (row0 < nN) {
        float dv = dinv[row0];
        uint2 val;
        val.x = f2bf(acc0[0] * dv) | (f2bf(acc0[1] * dv) << 16);
        val.y = f2bf(acc0[2] * dv) | (f2bf(acc0[3] * dv) << 16);
        *(uint2*)(Gc + ((size_t)c * (nN + 1) + row0) * 8 + w) = val;
    }
    if (row1 < nN) {
        float dv = dinv[row1];
        uint2 val;
        val.x = f2bf(acc1[0] * dv) | (f2bf(acc1[1] * dv) << 16);
        val.y = f2bf(acc1[2] * dv) | (f2bf(acc1[3] * dv) << 16);
        *(uint2*)(Gc + ((size_t)c * (nN + 1) + row1) * 8 + w) = val;
    }
}

// ---------- agg1: ILP-4 gather over chunk, write H chunk (bf16) ----------
__global__ void __launch_bounds__(256)
agg1v2(const int* __restrict__ rowptr, const int* __restrict__ rowend,
       const int* __restrict__ csrP, const unsigned* __restrict__ Gc,
       const float* __restrict__ dinv, const float* __restrict__ b1,
       unsigned* __restrict__ Hc, int nN, int K) {
    int b = blockIdx.x;
    int xcd = b & 7;
    int c = xcd & 1;
    int k = (b >> 3) * 4 + (xcd >> 1);
    if (k >= K) return;
    int t = threadIdx.x, wv = t >> 6, lane = t & 63;
    int node = k * 16 + wv * 4 + (lane >> 4);
    int slot = (lane >> 1) & 7, comp = lane & 1;
    bool vn = node < nN;
    const uint4* Gch = (const uint4*)(Gc + (size_t)c * (nN + 1) * 8);
    float a[8] = {0, 0, 0, 0, 0, 0, 0, 0};
    if (vn) {
        if ((lane & 14) == 0) bfacc8(a, Gch[(size_t)node * 2 + comp]);  // self-loop
        int beg = rowptr[node], endp = rowend[node];
        for (int e = beg + slot * 4; e < endp; e += 32) {
            int4 idx = *(const int4*)(csrP + e);
            uint4 r0 = Gch[(size_t)idx.x * 2 + comp];
            uint4 r1 = Gch[(size_t)idx.y * 2 + comp];
            uint4 r2 = Gch[(size_t)idx.z * 2 + comp];
            uint4 r3 = Gch[(size_t)idx.w * 2 + comp];
            bfacc8(a, r0); bfacc8(a, r1); bfacc8(a, r2); bfacc8(a, r3);
        }
    }
#pragma unroll
    for (int m = 2; m < 16; m <<= 1) {
#pragma unroll
        for (int i = 0; i < 8; ++i) a[i] += __shfl_xor(a[i], m);
    }
    if (vn && (lane & 14) == 0) {
        float dv = dinv[node];
        const float* bb = b1 + c * 16 + comp * 8;
        float h[8];
#pragma unroll
        for (int i = 0; i < 8; ++i) {
            float x1 = fmaxf(fmaf(dv, a[i], bb[i]), 0.f);
            h[i] = dv * x1;
        }
        uint4 hp;
        hp.x = f2bf(h[0]) | (f2bf(h[1]) << 16);
        hp.y = f2bf(h[2]) | (f2bf(h[3]) << 16);
        hp.z = f2bf(h[4]) | (f2bf(h[5]) << 16);
        hp.w = f2bf(h[6]) | (f2bf(h[7]) << 16);
        ((uint4*)(Hc + (size_t)c * (nN + 1) * 8))[(size_t)node * 2 + comp] = hp;
    }
}

// ---------- agg2: ILP-4 gather over H chunk, write A2 fp32 [nN][32] ----------
__global__ void __launch_bounds__(256)
agg2v2(const int* __restrict__ rowptr, const int* __restrict__ rowend,
       const int* __restrict__ csrP, const unsigned* __restrict__ Hc,
       const float* __restrict__ dinv, float* __restrict__ A2, int nN, int K) {
    int b = blockIdx.x;
    int xcd = b & 7;
    int c = xcd & 1;
    int k = (b >> 3) * 4 + (xcd >> 1);
    if (k >= K) return;
    int t = threadIdx.x, wv = t >> 6, lane = t & 63;
    int node = k * 16 + wv * 4 + (lane >> 4);
    int slot = (lane >> 1) & 7, comp = lane & 1;
    bool vn = node < nN;
    const uint4* Hch = (const uint4*)(Hc + (size_t)c * (nN + 1) * 8);
    float a[8] = {0, 0, 0, 0, 0, 0, 0, 0};
    if (vn) {
        if ((lane & 14) == 0) bfacc8(a, Hch[(size_t)node * 2 + comp]);  // self-loop
        int beg = rowptr[node], endp = rowend[node];
        for (int e = beg + slot * 4; e < endp; e += 32) {
            int4 idx = *(const int4*)(csrP + e);
            uint4 r0 = Hch[(size_t)idx.x * 2 + comp];
            uint4 r1 = Hch[(size_t)idx.y * 2 + comp];
            uint4 r2 = Hch[(size_t)idx.z * 2 + comp];
            uint4 r3 = Hch[(size_t)idx.w * 2 + comp];
            bfacc8(a, r0); bfacc8(a, r1); bfacc8(a, r2); bfacc8(a, r3);
        }
    }
#pragma unroll
    for (int m = 2; m < 16; m <<= 1) {
#pragma unroll
        for (int i = 0; i < 8; ++i) a[i] += __shfl_xor(a[i], m);
    }
    if (vn && (lane & 14) == 0) {
        float dv = dinv[node];
        float* dst = A2 + (size_t)node * F1 + c * 16 + comp * 8;
        float4 o0 = make_float4(dv * a[0], dv * a[1], dv * a[2], dv * a[3]);
        float4 o1 = make_float4(dv * a[4], dv * a[5], dv * a[6], dv * a[7]);
        ((float4*)dst)[0] = o0;
        ((float4*)dst)[1] = o1;
    }
}

// ---------- segmented pool of x1 from Hc (batch sorted; flush on graph change) ----------
__global__ void __launch_bounds__(256)
poolX1(const unsigned* __restrict__ Hc, const float* __restrict__ rs,
       const int* __restrict__ batch, float* __restrict__ psum, int nN) {
    int t = threadIdx.x, wv = t >> 6, lane = t & 63;
    int c = wv >> 1, half = wv & 1;
    int base = blockIdx.x * PNPB + half * (PNPB / 2);
    int w32 = lane & 7, noff = lane >> 3;
    const unsigned* Hch = Hc + (size_t)c * (nN + 1) * 8;
    int feat = c * 16 + w32 * 2;
    float a0 = 0.f, a1 = 0.f;
    int curG = -1;
#pragma unroll 4
    for (int i = 0; i < PNPB / 16; ++i) {
        int node = base + noff + 8 * i;
        if (node >= nN) break;
        int bg = batch[node];
        if (bg != curG) {
            if (curG >= 0) {
                atomicAdd(&psum[(size_t)curG * FJ + feat + 0], a0);
                atomicAdd(&psum[(size_t)curG * FJ + feat + 1], a1);
            }
            a0 = a1 = 0.f; curG = bg;
        }
        unsigned v = Hch[(size_t)node * 8 + w32];
        float r = rs[node];
        a0 = fmaf(bf2f(v & 0xffffu), r, a0);
        a1 = fmaf(bf2f(v >> 16), r, a1);
    }
    if (curG >= 0) {
        atomicAdd(&psum[(size_t)curG * FJ + feat + 0], a0);
        atomicAdd(&psum[(size_t)curG * FJ + feat + 1], a1);
    }
}

// ---------- segmented x2 pool v2: LDS-staged A2, 16 nodes/wave ----------
__global__ void __launch_bounds__(256)
poolX2(const float* __restrict__ A2, const float* __restrict__ W2,
       const float* __restrict__ b2, const int* __restrict__ batch,
       float* __restrict__ psum, int nN) {
    __shared__ float W2s[F1 * F2];
    __shared__ float aL[NP2][F1];
    int t = threadIdx.x;
    for (int i = t; i < F1 * F2; i += 256) W2s[i] = W2[i];
    int nbase = blockIdx.x * NP2;
    {
        const float4* A4 = (const float4*)(A2 + (size_t)nbase * F1);
        float4* aL4 = (float4*)aL;
        int total4 = NP2 * F1 / 4;
        for (int i = t; i < total4; i += 256) {
            int gnode = nbase + (i >> 3);
            aL4[i] = (gnode < nN) ? A4[i] : make_float4(0.f, 0.f, 0.f, 0.f);
        }
    }
    __syncthreads();
    int wv = t >> 6, lane = t & 63;
    int n0 = wv * (NP2 / 4);
    float bj = b2[lane];
    float acc = 0.f;
    int curG = -1;
    for (int i = 0; i < NP2 / 4; ++i) {
        int node = nbase + n0 + i;
        if (node >= nN) break;
        int bg = batch[node];
        if (bg != curG) {
            if (curG >= 0) atomicAdd(&psum[(size_t)curG * FJ + F1 + lane], acc);
            acc = 0.f; curG = bg;
        }
        const float* a = aL[n0 + i];
        float dot = 0.f;
#pragma unroll
        for (int k = 0; k < F1; ++k) dot = fmaf(a[k], W2s[k * F2 + lane], dot);
        acc += fmaxf(dot + bj, 0.f);
    }
    if (curG >= 0) atomicAdd(&psum[(size_t)curG * FJ + F1 + lane], acc);
}

// ---------- counts via binary search (batch sorted, no atomics) ----------
__global__ void cntBS(const int* __restrict__ batch, float* __restrict__ cnt,
                      int nN, int nG) {
    int g = blockIdx.x * blockDim.x + threadIdx.x;
    if (g >= nG) return;
    int lo = 0, hi = nN;
    while (lo < hi) { int m = (lo + hi) >> 1; if (batch[m] < g) lo = m + 1; else hi = m; }
    int s = lo;
    lo = 0; hi = nN;
    while (lo < hi) { int m = (lo + hi) >> 1; if (batch[m] < g + 1) lo = m + 1; else hi = m; }
    cnt[g] = (float)(lo - s);
}

__global__ void mlp_kernel(const float* __restrict__ psum, const float* __restrict__ cnt,
                           const float* __restrict__ fW1, const float* __restrict__ fb1,
                           const float* __restrict__ fW2, const float* __restrict__ fb2,
                           float* __restrict__ out) {
    __shared__ float p[FJ];
    __shared__ float red[FH];
    int g = blockIdx.x, tid = threadIdx.x;
    float c = fmaxf(cnt[g], 1.0f);
    if (tid < FJ) p[tid] = psum[g * FJ + tid] / c;
    __syncthreads();
    float acc = fb1[tid];
    for (int k = 0; k < FJ; ++k) acc = fmaf(p[k], fW1[k * FH + tid], acc);
    float h = fmaxf(acc, 0.f);
    red[tid] = h * fW2[tid];
    __syncthreads();
    for (int s = FH / 2; s > 0; s >>= 1) {
        if (tid < s) red[tid] += red[tid + s];
        __syncthreads();
    }
    if (tid == 0) out[g] = red[0] + fb2[0];
}

extern "C" void kernel_launch(void* const* d_in, const int* in_sizes, int n_in,
                              void* d_out, int out_size, void* d_ws, size_t ws_size,
                              hipStream_t stream) {
    const float* x   = (const float*)d_in[0];
    const int*   ei  = (const int*)d_in[1];
    const int*   bat = (const int*)d_in[2];
    const float* W1  = (const float*)d_in[3];
    const float* b1  = (const float*)d_in[4];
    const float* W2  = (const float*)d_in[5];
    const float* b2  = (const float*)d_in[6];
    const float* fW1 = (const float*)d_in[7];
    const float* fb1 = (const float*)d_in[8];
    const float* fW2 = (const float*)d_in[9];
    const float* fb2 = (const float*)d_in[10];
    float* out = (float*)d_out;

    int nN = in_sizes[0] / FEAT_IN;
    int nE = in_sizes[1] / 2;
    int nG = out_size;
    const int* src = ei;
    const int* dst = ei + nE;

    int nB   = (nN + BNODES - 1) >> BSH;
    int nCh  = (nE + CH - 1) / CH;
    int nChP = (nCh + 3) & ~3;           // int4-aligned chunk count
    int K    = (nN + 15) / 16;
    int gridC = ((K + 3) / 4) * 8;

    char* w = (char*)d_ws;
    auto alloc = [&](size_t bytes) { char* p = w; w += (bytes + 15) & ~(size_t)15; return p; };
    int*      gHistT = (int*)alloc((size_t)NBMAX * nChP * 4);
    int*      gBaseT = (int*)alloc((size_t)NBMAX * nChP * 4);
    int*      boff   = (int*)alloc((NBMAX + 1) * 4);
    unsigned* EB     = (unsigned*)alloc((size_t)nE * 4);
    int*      rowptr = (int*)alloc((size_t)nN * 4);
    int*      rowend = (int*)alloc((size_t)nN * 4);
    int*      csrP   = (int*)alloc(((size_t)nE + (size_t)NBMAX * PADMAX + 64) * 4);
    float*    dinv   = (float*)alloc((size_t)nN * 4);
    float*    rsb    = (float*)alloc((size_t)nN * 4);
    unsigned* Gc     = (unsigned*)alloc((size_t)2 * (nN + 1) * 16 * 2);
    unsigned* Hc     = (unsigned*)alloc((size_t)2 * (nN + 1) * 16 * 2);
    float*    A2     = (float*)alloc((size_t)(nN + NP2) * F1 * 4);
    float*    psum   = (float*)alloc((size_t)nG * FJ * 4);
    float*    cnt    = (float*)alloc((size_t)nG * 4);

    hipMemsetAsync(gHistT, 0, (size_t)nB * nChP * 4, stream);
    hipMemsetAsync(psum, 0, (size_t)nG * FJ * 4, stream);
    for (int c = 0; c < 2; ++c) {
        hipMemsetAsync(Gc + ((size_t)c * (nN + 1) + nN) * 16, 0, 32, stream);
        hipMemsetAsync(Hc + ((size_t)c * (nN + 1) + nN) * 16, 0, 32, stream);
    }

    // CSR build: per-chunk hist -> scan -> atomic-free scatter -> bucket sort
    histPB<<<nCh, 256, 0, stream>>>(dst, gHistT, nE, nB, nChP);
    scanAll<<<1, 512, 0, stream>>>(gHistT, gBaseT, boff, nB, nChP, nE);
    scatterEB2<<<nCh, 256, 0, stream>>>(src, dst, gBaseT, EB, nE, nB, nChP);
    bucketSortK<<<nB, 512, 0, stream>>>(EB, boff, rowptr, rowend, csrP, dinv, rsb, nN, nB);

    // layer 1
    gemm1v3<<<(nN + GR - 1) / GR, 256, 0, stream>>>((const float4*)x, W1, dinv, Gc, nN);
    agg1v2<<<gridC, 256, 0, stream>>>(rowptr, rowend, csrP, Gc, dinv, b1, Hc, nN, K);
    // layer 2
    agg2v2<<<gridC, 256, 0, stream>>>(rowptr, rowend, csrP, Hc, dinv, A2, nN, K);

    // segmented pooling + counts + MLP
    poolX1<<<(nN + PNPB - 1) / PNPB, 256, 0, stream>>>(Hc, rsb, bat, psum, nN);
    poolX2<<<(nN + NP2 - 1) / NP2, 256, 0, stream>>>(A2, W2, b2, bat, psum, nN);
    cntBS<<<(nG + 255) / 256, 256, 0, stream>>>(bat, cnt, nN, nG);
    mlp_kernel<<<nG, FH, 0, stream>>>(psum, cnt, fW1, fb1, fW2, fb2, out);
}

// Round 16
// 254.311 us; speedup vs baseline: 1.8388x; 1.8388x over previous
//
#include <hip/hip_runtime.h>
#include <stdint.h>

#define FEAT_IN 128
#define F1 32
#define F2 64
#define FJ 96
#define FH 128

#define BSH 8                  // 256 nodes per bucket
#define BNODES 256
#define NBMAX 512
#define CH 4096                // edges per scatter chunk
#define SRCBITS 17             // nN must be < 2^17
#define SRCMASK 0x1FFFFu
#define PADMAX 768             // max pad per bucket (256 nodes * 3)
#define PNPB 256               // nodes per block in poolX1
#define NP2 64                 // nodes per block in poolX2
#define GR 64                  // rows per block in gemm1v3
#define XPAD 132               // padded LDS row stride (floats) for x tile

__device__ __forceinline__ unsigned f2bf(float f) {
    unsigned u = __float_as_uint(f);
    return (u + 0x7FFFu + ((u >> 16) & 1u)) >> 16;   // RNE
}
__device__ __forceinline__ float bf2f(unsigned h) { return __uint_as_float(h << 16); }
__device__ __forceinline__ void bfacc8(float* a, uint4 v) {
    a[0] += bf2f(v.x & 0xffffu); a[1] += bf2f(v.x >> 16);
    a[2] += bf2f(v.y & 0xffffu); a[3] += bf2f(v.y >> 16);
    a[4] += bf2f(v.z & 0xffffu); a[5] += bf2f(v.z >> 16);
    a[6] += bf2f(v.w & 0xffffu); a[7] += bf2f(v.w >> 16);
}
__device__ __forceinline__ void fma4(float* acc, float s, float4 wv) {
    acc[0] = fmaf(s, wv.x, acc[0]);
    acc[1] = fmaf(s, wv.y, acc[1]);
    acc[2] = fmaf(s, wv.z, acc[2]);
    acc[3] = fmaf(s, wv.w, acc[3]);
}

// ---------- per-chunk bucket histogram -> gHistT[bucket][chunk] ----------
__global__ void histPB(const int* __restrict__ dst, int* __restrict__ gHistT,
                       int nE, int nB, int nChP) {
    __shared__ int h[NBMAX];
    int ck = blockIdx.x, t = threadIdx.x;
    int e0 = ck * CH;
    int ecnt = min(CH, nE - e0);
    if (ecnt <= 0) return;
    for (int i = t; i < nB; i += 256) h[i] = 0;
    __syncthreads();
    for (int i = t; i < ecnt; i += 256) atomicAdd(&h[dst[e0 + i] >> BSH], 1);
    __syncthreads();
    for (int b = t; b < nB; b += 256) gHistT[(size_t)b * nChP + ck] = h[b];
}

// ---------- wave-per-bucket scan over chunks: bucket-LOCAL bases + totals ----------
__global__ void __launch_bounds__(256)
scanWB(const int* __restrict__ gHistT, int* __restrict__ gBaseT,
       int* __restrict__ btot, int nB, int nChP) {
    int wv = blockIdx.x * 4 + (threadIdx.x >> 6);
    if (wv >= nB) return;
    int lane = threadIdx.x & 63;
    const int* hp = gHistT + (size_t)wv * nChP;
    int* gp = gBaseT + (size_t)wv * nChP;
    int running = 0;
    for (int c0 = 0; c0 < nChP; c0 += 64) {
        int ck = c0 + lane;
        int v = (ck < nChP) ? hp[ck] : 0;
        int incl = v;
#pragma unroll
        for (int off = 1; off < 64; off <<= 1) {
            int u = __shfl_up(incl, off);
            if (lane >= off) incl += u;
        }
        if (ck < nChP) gp[ck] = running + incl - v;
        running += __shfl(incl, 63);
    }
    if (lane == 0) btot[wv] = running;
}

// ---------- tiny single-block scan of bucket totals -> boff ----------
__global__ void __launch_bounds__(512)
scanOff(const int* __restrict__ btot, int* __restrict__ boff, int nB) {
    __shared__ int ps[512];
    int t = threadIdx.x;
    int v = (t < nB) ? btot[t] : 0;
    ps[t] = v; __syncthreads();
    for (int off = 1; off < 512; off <<= 1) {
        int u = (t >= off) ? ps[t - off] : 0; __syncthreads();
        ps[t] += u; __syncthreads();
    }
    int excl = ps[t] - v;
    if (t < nB) boff[t] = excl;
    if (t == nB - 1) boff[nB] = excl + v;
}

// ---------- scatter edges into buckets (no global atomics, LDS-staged) ----------
__global__ void __launch_bounds__(256)
scatterEB2(const int* __restrict__ src, const int* __restrict__ dst,
           const int* __restrict__ gBaseT, const int* __restrict__ boff,
           unsigned* __restrict__ EB, int nE, int nB, int nChP) {
    __shared__ int lh[NBMAX], loff[NBMAX], lcur[NBMAX], gbaseL[NBMAX];
    __shared__ int ps[256];
    __shared__ unsigned stagePack[CH];
    __shared__ unsigned short stageBkt[CH];
    int ck = blockIdx.x, t = threadIdx.x;
    int e0 = ck * CH;
    int ecnt = min(CH, nE - e0);
    if (ecnt <= 0) return;
    for (int i = t; i < nB; i += 256) lh[i] = 0;
    __syncthreads();
    for (int i = t; i < ecnt; i += 256) atomicAdd(&lh[dst[e0 + i] >> BSH], 1);
    __syncthreads();
    int b0 = 2 * t, b1 = 2 * t + 1;
    int c0 = (b0 < nB) ? lh[b0] : 0;
    int c1 = (b1 < nB) ? lh[b1] : 0;
    ps[t] = c0 + c1; __syncthreads();
    for (int off = 1; off < 256; off <<= 1) {
        int v = (t >= off) ? ps[t - off] : 0; __syncthreads();
        ps[t] += v; __syncthreads();
    }
    int excl = ps[t] - (c0 + c1);
    if (b0 < nB) { loff[b0] = excl;      lcur[b0] = excl;      gbaseL[b0] = boff[b0] + gBaseT[(size_t)b0 * nChP + ck]; }
    if (b1 < nB) { loff[b1] = excl + c0; lcur[b1] = excl + c0; gbaseL[b1] = boff[b1] + gBaseT[(size_t)b1 * nChP + ck]; }
    __syncthreads();
    for (int i = t; i < ecnt; i += 256) {
        int d = dst[e0 + i], s = src[e0 + i];
        int bkt = d >> BSH;
        int p = atomicAdd(&lcur[bkt], 1);
        stagePack[p] = (unsigned)s | ((unsigned)(d & (BNODES - 1)) << SRCBITS);
        stageBkt[p] = (unsigned short)bkt;
    }
    __syncthreads();
    for (int i = t; i < ecnt; i += 256) {
        int bb = stageBkt[i];
        EB[gbaseL[bb] + (i - loff[bb])] = stagePack[i];
    }
}

// ---------- per-bucket counting sort -> PADDED csr (x4, sentinel nN), dinv, rs ----------
__global__ void __launch_bounds__(512)
bucketSortK(const unsigned* __restrict__ EB, const int* __restrict__ boff,
            int* __restrict__ rowptr, int* __restrict__ rowend, int* __restrict__ csrP,
            float* __restrict__ dinv, float* __restrict__ rs, int nN, int nB) {
    __shared__ int hist[BNODES];
    __shared__ int cur[BNODES];
    __shared__ int ps[256];
    int b = blockIdx.x, t = threadIdx.x;
    int beg = boff[b], end = boff[b + 1];
    if (t < 256) hist[t] = 0;
    __syncthreads();
    for (int i = beg + t; i < end; i += 512) atomicAdd(&hist[EB[i] >> SRCBITS], 1);
    __syncthreads();
    int deg = (t < 256) ? hist[t] : 0;
    int pdeg = (deg + 3) & ~3;
    if (t < 256) ps[t] = pdeg;
    __syncthreads();
    for (int off = 1; off < 256; off <<= 1) {
        int v = (t >= off && t < 256) ? ps[t - off] : 0; __syncthreads();
        if (t < 256) ps[t] += v;
        __syncthreads();
    }
    int base = ((beg + 3) & ~3) + b * PADMAX;
    int excl = 0;
    if (t < 256) {
        excl = base + ps[t] - pdeg;
        int node = (b << BSH) + t;
        if (node < nN) {
            rowptr[node] = excl;
            rowend[node] = excl + pdeg;
            dinv[node] = rsqrtf((float)deg + 1.0f);
            rs[node] = sqrtf((float)deg + 1.0f);
        }
        cur[t] = excl;
    }
    __syncthreads();
    for (int i = beg + t; i < end; i += 512) {
        unsigned v = EB[i];
        int p = atomicAdd(&cur[v >> SRCBITS], 1);
        csrP[p] = (int)(v & SRCMASK);
    }
    __syncthreads();
    if (t < 256) {
        for (int p = cur[t]; p < excl + pdeg; ++p) csrP[p] = nN;
    }
}

// ---------- gemm1 v3: 2x4 register tile, 64 rows/block ----------
__global__ void __launch_bounds__(256)
gemm1v3(const float4* __restrict__ x4, const float* __restrict__ W1,
        const float* __restrict__ dinv, unsigned* __restrict__ Gc, int nN) {
    __shared__ float Ws[FEAT_IN * F1];   // 16 KB
    __shared__ float xs[GR * XPAD];      // 33 KB
    int t = threadIdx.x;
    for (int i = t; i < FEAT_IN * F1; i += 256) Ws[i] = W1[i];
    int rb = blockIdx.x * GR;
    for (int i = t; i < GR * 32; i += 256) {
        int r = i >> 5, c = i & 31;
        int row = rb + r;
        float4 v = (row < nN) ? x4[(size_t)row * 32 + c] : make_float4(0.f, 0.f, 0.f, 0.f);
        *(float4*)(xs + r * XPAD + c * 4) = v;
    }
    __syncthreads();
    int cg = t & 7, rg = t >> 3;
    int r0 = rg * 2, r1 = r0 + 1;
    int j0 = cg * 4;
    float acc0[4] = {0.f, 0.f, 0.f, 0.f};
    float acc1[4] = {0.f, 0.f, 0.f, 0.f};
    const float4* xa4 = (const float4*)(xs + r0 * XPAD);
    const float4* xb4 = (const float4*)(xs + r1 * XPAD);
    const float4* W4 = (const float4*)Ws;
#pragma unroll 4
    for (int kc = 0; kc < 32; ++kc) {
        float4 xa = xa4[kc];
        float4 xb = xb4[kc];
        float4 w0 = W4[(4 * kc + 0) * 8 + cg];
        float4 w1 = W4[(4 * kc + 1) * 8 + cg];
        float4 w2 = W4[(4 * kc + 2) * 8 + cg];
        float4 w3 = W4[(4 * kc + 3) * 8 + cg];
        fma4(acc0, xa.x, w0); fma4(acc0, xa.y, w1);
        fma4(acc0, xa.z, w2); fma4(acc0, xa.w, w3);
        fma4(acc1, xb.x, w0); fma4(acc1, xb.y, w1);
        fma4(acc1, xb.z, w2); fma4(acc1, xb.w, w3);
    }
    int c = j0 >> 4;
    int w = (j0 & 15) >> 1;
    int row0 = rb + r0, row1 = rb + r1;
    if (row0 < nN) {
        float dv = dinv[row0];
        uint2 val;
        val.x = f2bf(acc0[0] * dv) | (f2bf(acc0[1] * dv) << 16);
        val.y = f2bf(acc0[2] * dv) | (f2bf(acc0[3] * dv) << 16);
        *(uint2*)(Gc + ((size_t)c * (nN + 1) + row0) * 8 + w) = val;
    }
    if (row1 < nN) {
        float dv = dinv[row1];
        uint2 val;
        val.x = f2bf(acc1[0] * dv) | (f2bf(acc1[1] * dv) << 16);
        val.y = f2bf(acc1[2] * dv) | (f2bf(acc1[3] * dv) << 16);
        *(uint2*)(Gc + ((size_t)c * (nN + 1) + row1) * 8 + w) = val;
    }
}

// ---------- agg1: ILP-4 gather over chunk, write H chunk (bf16) ----------
__global__ void __launch_bounds__(256)
agg1v2(const int* __restrict__ rowptr, const int* __restrict__ rowend,
       const int* __restrict__ csrP, const unsigned* __restrict__ Gc,
       const float* __restrict__ dinv, const float* __restrict__ b1,
       unsigned* __restrict__ Hc, int nN, int K) {
    int b = blockIdx.x;
    int xcd = b & 7;
    int c = xcd & 1;
    int k = (b >> 3) * 4 + (xcd >> 1);
    if (k >= K) return;
    int t = threadIdx.x, wv = t >> 6, lane = t & 63;
    int node = k * 16 + wv * 4 + (lane >> 4);
    int slot = (lane >> 1) & 7, comp = lane & 1;
    bool vn = node < nN;
    const uint4* Gch = (const uint4*)(Gc + (size_t)c * (nN + 1) * 8);
    float a[8] = {0, 0, 0, 0, 0, 0, 0, 0};
    if (vn) {
        if ((lane & 14) == 0) bfacc8(a, Gch[(size_t)node * 2 + comp]);  // self-loop
        int beg = rowptr[node], endp = rowend[node];
        for (int e = beg + slot * 4; e < endp; e += 32) {
            int4 idx = *(const int4*)(csrP + e);
            uint4 r0 = Gch[(size_t)idx.x * 2 + comp];
            uint4 r1 = Gch[(size_t)idx.y * 2 + comp];
            uint4 r2 = Gch[(size_t)idx.z * 2 + comp];
            uint4 r3 = Gch[(size_t)idx.w * 2 + comp];
            bfacc8(a, r0); bfacc8(a, r1); bfacc8(a, r2); bfacc8(a, r3);
        }
    }
#pragma unroll
    for (int m = 2; m < 16; m <<= 1) {
#pragma unroll
        for (int i = 0; i < 8; ++i) a[i] += __shfl_xor(a[i], m);
    }
    if (vn && (lane & 14) == 0) {
        float dv = dinv[node];
        const float* bb = b1 + c * 16 + comp * 8;
        float h[8];
#pragma unroll
        for (int i = 0; i < 8; ++i) {
            float x1 = fmaxf(fmaf(dv, a[i], bb[i]), 0.f);
            h[i] = dv * x1;
        }
        uint4 hp;
        hp.x = f2bf(h[0]) | (f2bf(h[1]) << 16);
        hp.y = f2bf(h[2]) | (f2bf(h[3]) << 16);
        hp.z = f2bf(h[4]) | (f2bf(h[5]) << 16);
        hp.w = f2bf(h[6]) | (f2bf(h[7]) << 16);
        ((uint4*)(Hc + (size_t)c * (nN + 1) * 8))[(size_t)node * 2 + comp] = hp;
    }
}

// ---------- agg2: ILP-4 gather over H chunk, write A2 fp32 [nN][32] ----------
__global__ void __launch_bounds__(256)
agg2v2(const int* __restrict__ rowptr, const int* __restrict__ rowend,
       const int* __restrict__ csrP, const unsigned* __restrict__ Hc,
       const float* __restrict__ dinv, float* __restrict__ A2, int nN, int K) {
    int b = blockIdx.x;
    int xcd = b & 7;
    int c = xcd & 1;
    int k = (b >> 3) * 4 + (xcd >> 1);
    if (k >= K) return;
    int t = threadIdx.x, wv = t >> 6, lane = t & 63;
    int node = k * 16 + wv * 4 + (lane >> 4);
    int slot = (lane >> 1) & 7, comp = lane & 1;
    bool vn = node < nN;
    const uint4* Hch = (const uint4*)(Hc + (size_t)c * (nN + 1) * 8);
    float a[8] = {0, 0, 0, 0, 0, 0, 0, 0};
    if (vn) {
        if ((lane & 14) == 0) bfacc8(a, Hch[(size_t)node * 2 + comp]);  // self-loop
        int beg = rowptr[node], endp = rowend[node];
        for (int e = beg + slot * 4; e < endp; e += 32) {
            int4 idx = *(const int4*)(csrP + e);
            uint4 r0 = Hch[(size_t)idx.x * 2 + comp];
            uint4 r1 = Hch[(size_t)idx.y * 2 + comp];
            uint4 r2 = Hch[(size_t)idx.z * 2 + comp];
            uint4 r3 = Hch[(size_t)idx.w * 2 + comp];
            bfacc8(a, r0); bfacc8(a, r1); bfacc8(a, r2); bfacc8(a, r3);
        }
    }
#pragma unroll
    for (int m = 2; m < 16; m <<= 1) {
#pragma unroll
        for (int i = 0; i < 8; ++i) a[i] += __shfl_xor(a[i], m);
    }
    if (vn && (lane & 14) == 0) {
        float dv = dinv[node];
        float* dst = A2 + (size_t)node * F1 + c * 16 + comp * 8;
        float4 o0 = make_float4(dv * a[0], dv * a[1], dv * a[2], dv * a[3]);
        float4 o1 = make_float4(dv * a[4], dv * a[5], dv * a[6], dv * a[7]);
        ((float4*)dst)[0] = o0;
        ((float4*)dst)[1] = o1;
    }
}

// ---------- segmented pool of x1 from Hc (batch sorted; flush on graph change) ----------
__global__ void __launch_bounds__(256)
poolX1(const unsigned* __restrict__ Hc, const float* __restrict__ rs,
       const int* __restrict__ batch, float* __restrict__ psum, int nN) {
    int t = threadIdx.x, wv = t >> 6, lane = t & 63;
    int c = wv >> 1, half = wv & 1;
    int base = blockIdx.x * PNPB + half * (PNPB / 2);
    int w32 = lane & 7, noff = lane >> 3;
    const unsigned* Hch = Hc + (size_t)c * (nN + 1) * 8;
    int feat = c * 16 + w32 * 2;
    float a0 = 0.f, a1 = 0.f;
    int curG = -1;
#pragma unroll 4
    for (int i = 0; i < PNPB / 16; ++i) {
        int node = base + noff + 8 * i;
        if (node >= nN) break;
        int bg = batch[node];
        if (bg != curG) {
            if (curG >= 0) {
                atomicAdd(&psum[(size_t)curG * FJ + feat + 0], a0);
                atomicAdd(&psum[(size_t)curG * FJ + feat + 1], a1);
            }
            a0 = a1 = 0.f; curG = bg;
        }
        unsigned v = Hch[(size_t)node * 8 + w32];
        float r = rs[node];
        a0 = fmaf(bf2f(v & 0xffffu), r, a0);
        a1 = fmaf(bf2f(v >> 16), r, a1);
    }
    if (curG >= 0) {
        atomicAdd(&psum[(size_t)curG * FJ + feat + 0], a0);
        atomicAdd(&psum[(size_t)curG * FJ + feat + 1], a1);
    }
}

// ---------- segmented x2 pool v2: LDS-staged A2, 16 nodes/wave ----------
__global__ void __launch_bounds__(256)
poolX2(const float* __restrict__ A2, const float* __restrict__ W2,
       const float* __restrict__ b2, const int* __restrict__ batch,
       float* __restrict__ psum, int nN) {
    __shared__ float W2s[F1 * F2];
    __shared__ float aL[NP2][F1];
    int t = threadIdx.x;
    for (int i = t; i < F1 * F2; i += 256) W2s[i] = W2[i];
    int nbase = blockIdx.x * NP2;
    {
        const float4* A4 = (const float4*)(A2 + (size_t)nbase * F1);
        float4* aL4 = (float4*)aL;
        int total4 = NP2 * F1 / 4;
        for (int i = t; i < total4; i += 256) {
            int gnode = nbase + (i >> 3);
            aL4[i] = (gnode < nN) ? A4[i] : make_float4(0.f, 0.f, 0.f, 0.f);
        }
    }
    __syncthreads();
    int wv = t >> 6, lane = t & 63;
    int n0 = wv * (NP2 / 4);
    float bj = b2[lane];
    float acc = 0.f;
    int curG = -1;
    for (int i = 0; i < NP2 / 4; ++i) {
        int node = nbase + n0 + i;
        if (node >= nN) break;
        int bg = batch[node];
        if (bg != curG) {
            if (curG >= 0) atomicAdd(&psum[(size_t)curG * FJ + F1 + lane], acc);
            acc = 0.f; curG = bg;
        }
        const float* a = aL[n0 + i];
        float dot = 0.f;
#pragma unroll
        for (int k = 0; k < F1; ++k) dot = fmaf(a[k], W2s[k * F2 + lane], dot);
        acc += fmaxf(dot + bj, 0.f);
    }
    if (curG >= 0) atomicAdd(&psum[(size_t)curG * FJ + F1 + lane], acc);
}

// ---------- counts via binary search (batch sorted, no atomics) ----------
__global__ void cntBS(const int* __restrict__ batch, float* __restrict__ cnt,
                      int nN, int nG) {
    int g = blockIdx.x * blockDim.x + threadIdx.x;
    if (g >= nG) return;
    int lo = 0, hi = nN;
    while (lo < hi) { int m = (lo + hi) >> 1; if (batch[m] < g) lo = m + 1; else hi = m; }
    int s = lo;
    lo = 0; hi = nN;
    while (lo < hi) { int m = (lo + hi) >> 1; if (batch[m] < g + 1) lo = m + 1; else hi = m; }
    cnt[g] = (float)(lo - s);
}

__global__ void mlp_kernel(const float* __restrict__ psum, const float* __restrict__ cnt,
                           const float* __restrict__ fW1, const float* __restrict__ fb1,
                           const float* __restrict__ fW2, const float* __restrict__ fb2,
                           float* __restrict__ out) {
    __shared__ float p[FJ];
    __shared__ float red[FH];
    int g = blockIdx.x, tid = threadIdx.x;
    float c = fmaxf(cnt[g], 1.0f);
    if (tid < FJ) p[tid] = psum[g * FJ + tid] / c;
    __syncthreads();
    float acc = fb1[tid];
    for (int k = 0; k < FJ; ++k) acc = fmaf(p[k], fW1[k * FH + tid], acc);
    float h = fmaxf(acc, 0.f);
    red[tid] = h * fW2[tid];
    __syncthreads();
    for (int s = FH / 2; s > 0; s >>= 1) {
        if (tid < s) red[tid] += red[tid + s];
        __syncthreads();
    }
    if (tid == 0) out[g] = red[0] + fb2[0];
}

extern "C" void kernel_launch(void* const* d_in, const int* in_sizes, int n_in,
                              void* d_out, int out_size, void* d_ws, size_t ws_size,
                              hipStream_t stream) {
    const float* x   = (const float*)d_in[0];
    const int*   ei  = (const int*)d_in[1];
    const int*   bat = (const int*)d_in[2];
    const float* W1  = (const float*)d_in[3];
    const float* b1  = (const float*)d_in[4];
    const float* W2  = (const float*)d_in[5];
    const float* b2  = (const float*)d_in[6];
    const float* fW1 = (const float*)d_in[7];
    const float* fb1 = (const float*)d_in[8];
    const float* fW2 = (const float*)d_in[9];
    const float* fb2 = (const float*)d_in[10];
    float* out = (float*)d_out;

    int nN = in_sizes[0] / FEAT_IN;
    int nE = in_sizes[1] / 2;
    int nG = out_size;
    const int* src = ei;
    const int* dst = ei + nE;

    int nB   = (nN + BNODES - 1) >> BSH;
    int nCh  = (nE + CH - 1) / CH;
    int nChP = (nCh + 3) & ~3;
    int K    = (nN + 15) / 16;
    int gridC = ((K + 3) / 4) * 8;

    char* w = (char*)d_ws;
    auto alloc = [&](size_t bytes) { char* p = w; w += (bytes + 15) & ~(size_t)15; return p; };
    int*      gHistT = (int*)alloc((size_t)NBMAX * nChP * 4);
    int*      gBaseT = (int*)alloc((size_t)NBMAX * nChP * 4);
    int*      btot   = (int*)alloc(NBMAX * 4);
    int*      boff   = (int*)alloc((NBMAX + 1) * 4);
    unsigned* EB     = (unsigned*)alloc((size_t)nE * 4);
    int*      rowptr = (int*)alloc((size_t)nN * 4);
    int*      rowend = (int*)alloc((size_t)nN * 4);
    int*      csrP   = (int*)alloc(((size_t)nE + (size_t)NBMAX * PADMAX + 64) * 4);
    float*    dinv   = (float*)alloc((size_t)nN * 4);
    float*    rsb    = (float*)alloc((size_t)nN * 4);
    unsigned* Gc     = (unsigned*)alloc((size_t)2 * (nN + 1) * 16 * 2);
    unsigned* Hc     = (unsigned*)alloc((size_t)2 * (nN + 1) * 16 * 2);
    float*    A2     = (float*)alloc((size_t)(nN + NP2) * F1 * 4);
    float*    psum   = (float*)alloc((size_t)nG * FJ * 4);
    float*    cnt    = (float*)alloc((size_t)nG * 4);

    hipMemsetAsync(gHistT, 0, (size_t)nB * nChP * 4, stream);
    hipMemsetAsync(psum, 0, (size_t)nG * FJ * 4, stream);
    for (int c = 0; c < 2; ++c) {
        hipMemsetAsync(Gc + ((size_t)c * (nN + 1) + nN) * 16, 0, 32, stream);
        hipMemsetAsync(Hc + ((size_t)c * (nN + 1) + nN) * 16, 0, 32, stream);
    }

    // CSR build: per-chunk hist -> wave-parallel scan -> atomic-free scatter -> sort
    histPB<<<nCh, 256, 0, stream>>>(dst, gHistT, nE, nB, nChP);
    scanWB<<<(nB + 3) / 4, 256, 0, stream>>>(gHistT, gBaseT, btot, nB, nChP);
    scanOff<<<1, 512, 0, stream>>>(btot, boff, nB);
    scatterEB2<<<nCh, 256, 0, stream>>>(src, dst, gBaseT, boff, EB, nE, nB, nChP);
    bucketSortK<<<nB, 512, 0, stream>>>(EB, boff, rowptr, rowend, csrP, dinv, rsb, nN, nB);

    // layer 1
    gemm1v3<<<(nN + GR - 1) / GR, 256, 0, stream>>>((const float4*)x, W1, dinv, Gc, nN);
    agg1v2<<<gridC, 256, 0, stream>>>(rowptr, rowend, csrP, Gc, dinv, b1, Hc, nN, K);
    // layer 2
    agg2v2<<<gridC, 256, 0, stream>>>(rowptr, rowend, csrP, Hc, dinv, A2, nN, K);

    // segmented pooling + counts + MLP
    poolX1<<<(nN + PNPB - 1) / PNPB, 256, 0, stream>>>(Hc, rsb, bat, psum, nN);
    poolX2<<<(nN + NP2 - 1) / NP2, 256, 0, stream>>>(A2, W2, b2, bat, psum, nN);
    cntBS<<<(nG + 255) / 256, 256, 0, stream>>>(bat, cnt, nN, nG);
    mlp_kernel<<<nG, FH, 0, stream>>>(psum, cnt, fW1, fb1, fW2, fb2, out);
}

// Round 17
// 237.580 us; speedup vs baseline: 1.9683x; 1.0704x over previous
//
#include <hip/hip_runtime.h>
#include <stdint.h>

#define FEAT_IN 128
#define F1 32
#define F2 64
#define FJ 96
#define FH 128

#define BSH 8                  // 256 nodes per bucket
#define BNODES 256
#define NBMAX 512
#define CH 4096                // edges per scatter chunk
#define SRCBITS 17             // nN must be < 2^17
#define SRCMASK 0x1FFFFu
#define PADMAX 768             // max pad per bucket (256 nodes * 3)
#define PNPB 256               // nodes per block in poolX1
#define NP2 64                 // nodes per block in poolX2
#define GR 64                  // rows per block in gemm1v3
#define XPAD 132               // padded LDS row stride (floats) for x tile

__device__ __forceinline__ unsigned f2bf(float f) {
    unsigned u = __float_as_uint(f);
    return (u + 0x7FFFu + ((u >> 16) & 1u)) >> 16;   // RNE
}
__device__ __forceinline__ float bf2f_lo(unsigned u) { return __uint_as_float(u << 16); }
__device__ __forceinline__ float bf2f_hi(unsigned u) { return __uint_as_float(u & 0xffff0000u); }
// cheap unpack: lo = u<<16, hi = u & 0xffff0000 (no double-shift)
__device__ __forceinline__ void bfacc8(float* a, uint4 v) {
    a[0] += bf2f_lo(v.x); a[1] += bf2f_hi(v.x);
    a[2] += bf2f_lo(v.y); a[3] += bf2f_hi(v.y);
    a[4] += bf2f_lo(v.z); a[5] += bf2f_hi(v.z);
    a[6] += bf2f_lo(v.w); a[7] += bf2f_hi(v.w);
}
__device__ __forceinline__ void fma4(float* acc, float s, float4 wv) {
    acc[0] = fmaf(s, wv.x, acc[0]);
    acc[1] = fmaf(s, wv.y, acc[1]);
    acc[2] = fmaf(s, wv.z, acc[2]);
    acc[3] = fmaf(s, wv.w, acc[3]);
}

// ---------- per-chunk bucket histogram -> gHist[chunk][bucket] (coalesced) ----------
__global__ void histPB(const int* __restrict__ dst, int* __restrict__ gHist,
                       int nE, int nB) {
    __shared__ int h[NBMAX];
    int ck = blockIdx.x, t = threadIdx.x;
    int e0 = ck * CH;
    int ecnt = min(CH, nE - e0);
    if (ecnt <= 0) return;
    for (int i = t; i < nB; i += 256) h[i] = 0;
    __syncthreads();
    for (int i = t; i < ecnt; i += 256) atomicAdd(&h[dst[e0 + i] >> BSH], 1);
    __syncthreads();
    for (int b = t; b < nB; b += 256) gHist[(size_t)ck * NBMAX + b] = h[b];
}

// ---------- wave-per-bucket scan over chunks: bucket-LOCAL bases + totals ----------
__global__ void __launch_bounds__(256)
scanWB(const int* __restrict__ gHist, int* __restrict__ gBaseT,
       int* __restrict__ btot, int nB, int nChP) {
    int wv = blockIdx.x * 4 + (threadIdx.x >> 6);
    if (wv >= nB) return;
    int lane = threadIdx.x & 63;
    int* gp = gBaseT + (size_t)wv * nChP;
    int running = 0;
    for (int c0 = 0; c0 < nChP; c0 += 64) {
        int ck = c0 + lane;
        int v = (ck < nChP) ? gHist[(size_t)ck * NBMAX + wv] : 0;
        int incl = v;
#pragma unroll
        for (int off = 1; off < 64; off <<= 1) {
            int u = __shfl_up(incl, off);
            if (lane >= off) incl += u;
        }
        if (ck < nChP) gp[ck] = running + incl - v;
        running += __shfl(incl, 63);
    }
    if (lane == 0) btot[wv] = running;
}

// ---------- tiny single-block scan of bucket totals -> boff ----------
__global__ void __launch_bounds__(512)
scanOff(const int* __restrict__ btot, int* __restrict__ boff, int nB) {
    __shared__ int ps[512];
    int t = threadIdx.x;
    int v = (t < nB) ? btot[t] : 0;
    ps[t] = v; __syncthreads();
    for (int off = 1; off < 512; off <<= 1) {
        int u = (t >= off) ? ps[t - off] : 0; __syncthreads();
        ps[t] += u; __syncthreads();
    }
    int excl = ps[t] - v;
    if (t < nB) boff[t] = excl;
    if (t == nB - 1) boff[nB] = excl + v;
}

// ---------- scatter edges into buckets (no global atomics, LDS-staged) ----------
__global__ void __launch_bounds__(256)
scatterEB2(const int* __restrict__ src, const int* __restrict__ dst,
           const int* __restrict__ gBaseT, const int* __restrict__ boff,
           unsigned* __restrict__ EB, int nE, int nB, int nChP) {
    __shared__ int lh[NBMAX], loff[NBMAX], lcur[NBMAX], gbaseL[NBMAX];
    __shared__ int ps[256];
    __shared__ unsigned stagePack[CH];
    __shared__ unsigned short stageBkt[CH];
    int ck = blockIdx.x, t = threadIdx.x;
    int e0 = ck * CH;
    int ecnt = min(CH, nE - e0);
    if (ecnt <= 0) return;
    for (int i = t; i < nB; i += 256) lh[i] = 0;
    __syncthreads();
    for (int i = t; i < ecnt; i += 256) atomicAdd(&lh[dst[e0 + i] >> BSH], 1);
    __syncthreads();
    int b0 = 2 * t, b1 = 2 * t + 1;
    int c0 = (b0 < nB) ? lh[b0] : 0;
    int c1 = (b1 < nB) ? lh[b1] : 0;
    ps[t] = c0 + c1; __syncthreads();
    for (int off = 1; off < 256; off <<= 1) {
        int v = (t >= off) ? ps[t - off] : 0; __syncthreads();
        ps[t] += v; __syncthreads();
    }
    int excl = ps[t] - (c0 + c1);
    if (b0 < nB) { loff[b0] = excl;      lcur[b0] = excl;      gbaseL[b0] = boff[b0] + gBaseT[(size_t)b0 * nChP + ck]; }
    if (b1 < nB) { loff[b1] = excl + c0; lcur[b1] = excl + c0; gbaseL[b1] = boff[b1] + gBaseT[(size_t)b1 * nChP + ck]; }
    __syncthreads();
    for (int i = t; i < ecnt; i += 256) {
        int d = dst[e0 + i], s = src[e0 + i];
        int bkt = d >> BSH;
        int p = atomicAdd(&lcur[bkt], 1);
        stagePack[p] = (unsigned)s | ((unsigned)(d & (BNODES - 1)) << SRCBITS);
        stageBkt[p] = (unsigned short)bkt;
    }
    __syncthreads();
    for (int i = t; i < ecnt; i += 256) {
        int bb = stageBkt[i];
        EB[gbaseL[bb] + (i - loff[bb])] = stagePack[i];
    }
}

// ---------- per-bucket counting sort -> PADDED csr (x4, sentinel nN), dinv, rs ----------
__global__ void __launch_bounds__(512)
bucketSortK(const unsigned* __restrict__ EB, const int* __restrict__ boff,
            int* __restrict__ rowptr, int* __restrict__ rowend, int* __restrict__ csrP,
            float* __restrict__ dinv, float* __restrict__ rs, int nN, int nB) {
    __shared__ int hist[BNODES];
    __shared__ int cur[BNODES];
    __shared__ int ps[256];
    int b = blockIdx.x, t = threadIdx.x;
    int beg = boff[b], end = boff[b + 1];
    if (t < 256) hist[t] = 0;
    __syncthreads();
    for (int i = beg + t; i < end; i += 512) atomicAdd(&hist[EB[i] >> SRCBITS], 1);
    __syncthreads();
    int deg = (t < 256) ? hist[t] : 0;
    int pdeg = (deg + 3) & ~3;
    if (t < 256) ps[t] = pdeg;
    __syncthreads();
    for (int off = 1; off < 256; off <<= 1) {
        int v = (t >= off && t < 256) ? ps[t - off] : 0; __syncthreads();
        if (t < 256) ps[t] += v;
        __syncthreads();
    }
    int base = ((beg + 3) & ~3) + b * PADMAX;
    int excl = 0;
    if (t < 256) {
        excl = base + ps[t] - pdeg;
        int node = (b << BSH) + t;
        if (node < nN) {
            rowptr[node] = excl;
            rowend[node] = excl + pdeg;
            dinv[node] = rsqrtf((float)deg + 1.0f);
            rs[node] = sqrtf((float)deg + 1.0f);
        }
        cur[t] = excl;
    }
    __syncthreads();
    for (int i = beg + t; i < end; i += 512) {
        unsigned v = EB[i];
        int p = atomicAdd(&cur[v >> SRCBITS], 1);
        csrP[p] = (int)(v & SRCMASK);
    }
    __syncthreads();
    if (t < 256) {
        for (int p = cur[t]; p < excl + pdeg; ++p) csrP[p] = nN;
    }
}

// ---------- gemm1 v3: 2x4 register tile, 64 rows/block; block 0 zeroes sentinels ----------
__global__ void __launch_bounds__(256)
gemm1v3(const float4* __restrict__ x4, const float* __restrict__ W1,
        const float* __restrict__ dinv, unsigned* __restrict__ Gc,
        unsigned* __restrict__ Hc, int nN) {
    __shared__ float Ws[FEAT_IN * F1];   // 16 KB
    __shared__ float xs[GR * XPAD];      // 33 KB
    int t = threadIdx.x;
    if (blockIdx.x == 0 && t < 16) {     // zero sentinel rows (node nN), both chunks
        Gc[((size_t)(t >> 3) * (nN + 1) + nN) * 8 + (t & 7)] = 0u;
        Hc[((size_t)(t >> 3) * (nN + 1) + nN) * 8 + (t & 7)] = 0u;
    }
    for (int i = t; i < FEAT_IN * F1; i += 256) Ws[i] = W1[i];
    int rb = blockIdx.x * GR;
    for (int i = t; i < GR * 32; i += 256) {
        int r = i >> 5, c = i & 31;
        int row = rb + r;
        float4 v = (row < nN) ? x4[(size_t)row * 32 + c] : make_float4(0.f, 0.f, 0.f, 0.f);
        *(float4*)(xs + r * XPAD + c * 4) = v;
    }
    __syncthreads();
    int cg = t & 7, rg = t >> 3;
    int r0 = rg * 2, r1 = r0 + 1;
    int j0 = cg * 4;
    float acc0[4] = {0.f, 0.f, 0.f, 0.f};
    float acc1[4] = {0.f, 0.f, 0.f, 0.f};
    const float4* xa4 = (const float4*)(xs + r0 * XPAD);
    const float4* xb4 = (const float4*)(xs + r1 * XPAD);
    const float4* W4 = (const float4*)Ws;
#pragma unroll 4
    for (int kc = 0; kc < 32; ++kc) {
        float4 xa = xa4[kc];
        float4 xb = xb4[kc];
        float4 w0 = W4[(4 * kc + 0) * 8 + cg];
        float4 w1 = W4[(4 * kc + 1) * 8 + cg];
        float4 w2 = W4[(4 * kc + 2) * 8 + cg];
        float4 w3 = W4[(4 * kc + 3) * 8 + cg];
        fma4(acc0, xa.x, w0); fma4(acc0, xa.y, w1);
        fma4(acc0, xa.z, w2); fma4(acc0, xa.w, w3);
        fma4(acc1, xb.x, w0); fma4(acc1, xb.y, w1);
        fma4(acc1, xb.z, w2); fma4(acc1, xb.w, w3);
    }
    int c = j0 >> 4;
    int w = (j0 & 15) >> 1;
    int row0 = rb + r0, row1 = rb + r1;
    if (row0 < nN) {
        float dv = dinv[row0];
        uint2 val;
        val.x = f2bf(acc0[0] * dv) | (f2bf(acc0[1] * dv) << 16);
        val.y = f2bf(acc0[2] * dv) | (f2bf(acc0[3] * dv) << 16);
        *(uint2*)(Gc + ((size_t)c * (nN + 1) + row0) * 8 + w) = val;
    }
    if (row1 < nN) {
        float dv = dinv[row1];
        uint2 val;
        val.x = f2bf(acc1[0] * dv) | (f2bf(acc1[1] * dv) << 16);
        val.y = f2bf(acc1[2] * dv) | (f2bf(acc1[3] * dv) << 16);
        *(uint2*)(Gc + ((size_t)c * (nN + 1) + row1) * 8 + w) = val;
    }
}

// ---------- agg1: ILP-4 gather over chunk, write H chunk (bf16) ----------
__global__ void __launch_bounds__(256)
agg1v2(const int* __restrict__ rowptr, const int* __restrict__ rowend,
       const int* __restrict__ csrP, const unsigned* __restrict__ Gc,
       const float* __restrict__ dinv, const float* __restrict__ b1,
       unsigned* __restrict__ Hc, int nN, int K) {
    int b = blockIdx.x;
    int xcd = b & 7;
    int c = xcd & 1;
    int k = (b >> 3) * 4 + (xcd >> 1);
    if (k >= K) return;
    int t = threadIdx.x, wv = t >> 6, lane = t & 63;
    int node = k * 16 + wv * 4 + (lane >> 4);
    int slot = (lane >> 1) & 7, comp = lane & 1;
    bool vn = node < nN;
    const uint4* Gch = (const uint4*)(Gc + (size_t)c * (nN + 1) * 8);
    float a[8] = {0, 0, 0, 0, 0, 0, 0, 0};
    if (vn) {
        if ((lane & 14) == 0) bfacc8(a, Gch[(size_t)node * 2 + comp]);  // self-loop
        int beg = rowptr[node], endp = rowend[node];
        for (int e = beg + slot * 4; e < endp; e += 32) {
            int4 idx = *(const int4*)(csrP + e);
            uint4 r0 = Gch[(size_t)idx.x * 2 + comp];
            uint4 r1 = Gch[(size_t)idx.y * 2 + comp];
            uint4 r2 = Gch[(size_t)idx.z * 2 + comp];
            uint4 r3 = Gch[(size_t)idx.w * 2 + comp];
            bfacc8(a, r0); bfacc8(a, r1); bfacc8(a, r2); bfacc8(a, r3);
        }
    }
#pragma unroll
    for (int m = 2; m < 16; m <<= 1) {
#pragma unroll
        for (int i = 0; i < 8; ++i) a[i] += __shfl_xor(a[i], m);
    }
    if (vn && (lane & 14) == 0) {
        float dv = dinv[node];
        const float* bb = b1 + c * 16 + comp * 8;
        float h[8];
#pragma unroll
        for (int i = 0; i < 8; ++i) {
            float x1 = fmaxf(fmaf(dv, a[i], bb[i]), 0.f);
            h[i] = dv * x1;
        }
        uint4 hp;
        hp.x = f2bf(h[0]) | (f2bf(h[1]) << 16);
        hp.y = f2bf(h[2]) | (f2bf(h[3]) << 16);
        hp.z = f2bf(h[4]) | (f2bf(h[5]) << 16);
        hp.w = f2bf(h[6]) | (f2bf(h[7]) << 16);
        ((uint4*)(Hc + (size_t)c * (nN + 1) * 8))[(size_t)node * 2 + comp] = hp;
    }
}

// ---------- agg2: ILP-4 gather over H chunk, write A2 bf16 [nN][32] ----------
__global__ void __launch_bounds__(256)
agg2v2(const int* __restrict__ rowptr, const int* __restrict__ rowend,
       const int* __restrict__ csrP, const unsigned* __restrict__ Hc,
       const float* __restrict__ dinv, unsigned* __restrict__ A2b, int nN, int K) {
    int b = blockIdx.x;
    int xcd = b & 7;
    int c = xcd & 1;
    int k = (b >> 3) * 4 + (xcd >> 1);
    if (k >= K) return;
    int t = threadIdx.x, wv = t >> 6, lane = t & 63;
    int node = k * 16 + wv * 4 + (lane >> 4);
    int slot = (lane >> 1) & 7, comp = lane & 1;
    bool vn = node < nN;
    const uint4* Hch = (const uint4*)(Hc + (size_t)c * (nN + 1) * 8);
    float a[8] = {0, 0, 0, 0, 0, 0, 0, 0};
    if (vn) {
        if ((lane & 14) == 0) bfacc8(a, Hch[(size_t)node * 2 + comp]);  // self-loop
        int beg = rowptr[node], endp = rowend[node];
        for (int e = beg + slot * 4; e < endp; e += 32) {
            int4 idx = *(const int4*)(csrP + e);
            uint4 r0 = Hch[(size_t)idx.x * 2 + comp];
            uint4 r1 = Hch[(size_t)idx.y * 2 + comp];
            uint4 r2 = Hch[(size_t)idx.z * 2 + comp];
            uint4 r3 = Hch[(size_t)idx.w * 2 + comp];
            bfacc8(a, r0); bfacc8(a, r1); bfacc8(a, r2); bfacc8(a, r3);
        }
    }
#pragma unroll
    for (int m = 2; m < 16; m <<= 1) {
#pragma unroll
        for (int i = 0; i < 8; ++i) a[i] += __shfl_xor(a[i], m);
    }
    if (vn && (lane & 14) == 0) {
        float dv = dinv[node];
        uint4 o;
        o.x = f2bf(dv * a[0]) | (f2bf(dv * a[1]) << 16);
        o.y = f2bf(dv * a[2]) | (f2bf(dv * a[3]) << 16);
        o.z = f2bf(dv * a[4]) | (f2bf(dv * a[5]) << 16);
        o.w = f2bf(dv * a[6]) | (f2bf(dv * a[7]) << 16);
        ((uint4*)(A2b + (size_t)node * 16))[c * 2 + comp] = o;
    }
}

// ---------- segmented pool of x1 from Hc (batch sorted; flush on graph change) ----------
__global__ void __launch_bounds__(256)
poolX1(const unsigned* __restrict__ Hc, const float* __restrict__ rs,
       const int* __restrict__ batch, float* __restrict__ psum, int nN) {
    int t = threadIdx.x, wv = t >> 6, lane = t & 63;
    int c = wv >> 1, half = wv & 1;
    int base = blockIdx.x * PNPB + half * (PNPB / 2);
    int w32 = lane & 7, noff = lane >> 3;
    const unsigned* Hch = Hc + (size_t)c * (nN + 1) * 8;
    int feat = c * 16 + w32 * 2;
    float a0 = 0.f, a1 = 0.f;
    int curG = -1;
#pragma unroll 4
    for (int i = 0; i < PNPB / 16; ++i) {
        int node = base + noff + 8 * i;
        if (node >= nN) break;
        int bg = batch[node];
        if (bg != curG) {
            if (curG >= 0) {
                atomicAdd(&psum[(size_t)curG * FJ + feat + 0], a0);
                atomicAdd(&psum[(size_t)curG * FJ + feat + 1], a1);
            }
            a0 = a1 = 0.f; curG = bg;
        }
        unsigned v = Hch[(size_t)node * 8 + w32];
        float r = rs[node];
        a0 = fmaf(bf2f_lo(v), r, a0);
        a1 = fmaf(bf2f_hi(v), r, a1);
    }
    if (curG >= 0) {
        atomicAdd(&psum[(size_t)curG * FJ + feat + 0], a0);
        atomicAdd(&psum[(size_t)curG * FJ + feat + 1], a1);
    }
}

// ---------- segmented x2 pool: bf16 A2 LDS-staged, 16 nodes/wave ----------
__global__ void __launch_bounds__(256)
poolX2(const unsigned* __restrict__ A2b, const float* __restrict__ W2,
       const float* __restrict__ b2, const int* __restrict__ batch,
       float* __restrict__ psum, int nN) {
    __shared__ float W2s[F1 * F2];
    __shared__ float aL[NP2][F1];
    int t = threadIdx.x;
    for (int i = t; i < F1 * F2; i += 256) W2s[i] = W2[i];
    int nbase = blockIdx.x * NP2;
    {
        const uint4* A4 = (const uint4*)(A2b + (size_t)nbase * 16);
        for (int i = t; i < NP2 * 4; i += 256) {     // 256 uint4 per block
            int gnode = nbase + (i >> 2);
            uint4 v = (gnode < nN) ? A4[i] : make_uint4(0u, 0u, 0u, 0u);
            float* d = aL[i >> 2] + (i & 3) * 8;
            d[0] = bf2f_lo(v.x); d[1] = bf2f_hi(v.x);
            d[2] = bf2f_lo(v.y); d[3] = bf2f_hi(v.y);
            d[4] = bf2f_lo(v.z); d[5] = bf2f_hi(v.z);
            d[6] = bf2f_lo(v.w); d[7] = bf2f_hi(v.w);
        }
    }
    __syncthreads();
    int wv = t >> 6, lane = t & 63;
    int n0 = wv * (NP2 / 4);
    float bj = b2[lane];
    float acc = 0.f;
    int curG = -1;
    for (int i = 0; i < NP2 / 4; ++i) {
        int node = nbase + n0 + i;
        if (node >= nN) break;
        int bg = batch[node];
        if (bg != curG) {
            if (curG >= 0) atomicAdd(&psum[(size_t)curG * FJ + F1 + lane], acc);
            acc = 0.f; curG = bg;
        }
        const float* a = aL[n0 + i];
        float dot = 0.f;
#pragma unroll
        for (int k = 0; k < F1; ++k) dot = fmaf(a[k], W2s[k * F2 + lane], dot);
        acc += fmaxf(dot + bj, 0.f);
    }
    if (curG >= 0) atomicAdd(&psum[(size_t)curG * FJ + F1 + lane], acc);
}

// ---------- final MLP; per-block count via binary search (cntBS folded in) ----------
__global__ void mlp_kernel(const float* __restrict__ psum, const int* __restrict__ batch,
                           int nN,
                           const float* __restrict__ fW1, const float* __restrict__ fb1,
                           const float* __restrict__ fW2, const float* __restrict__ fb2,
                           float* __restrict__ out) {
    __shared__ float p[FJ];
    __shared__ float red[FH];
    __shared__ float cinv;
    int g = blockIdx.x, tid = threadIdx.x;
    if (tid == 0) {
        int lo = 0, hi = nN;
        while (lo < hi) { int m = (lo + hi) >> 1; if (batch[m] < g) lo = m + 1; else hi = m; }
        int s = lo;
        lo = 0; hi = nN;
        while (lo < hi) { int m = (lo + hi) >> 1; if (batch[m] < g + 1) lo = m + 1; else hi = m; }
        cinv = 1.0f / fmaxf((float)(lo - s), 1.0f);
    }
    __syncthreads();
    if (tid < FJ) p[tid] = psum[g * FJ + tid] * cinv;
    __syncthreads();
    float acc = fb1[tid];
    for (int k = 0; k < FJ; ++k) acc = fmaf(p[k], fW1[k * FH + tid], acc);
    float h = fmaxf(acc, 0.f);
    red[tid] = h * fW2[tid];
    __syncthreads();
    for (int s = FH / 2; s > 0; s >>= 1) {
        if (tid < s) red[tid] += red[tid + s];
        __syncthreads();
    }
    if (tid == 0) out[g] = red[0] + fb2[0];
}

extern "C" void kernel_launch(void* const* d_in, const int* in_sizes, int n_in,
                              void* d_out, int out_size, void* d_ws, size_t ws_size,
                              hipStream_t stream) {
    const float* x   = (const float*)d_in[0];
    const int*   ei  = (const int*)d_in[1];
    const int*   bat = (const int*)d_in[2];
    const float* W1  = (const float*)d_in[3];
    const float* b1  = (const float*)d_in[4];
    const float* W2  = (const float*)d_in[5];
    const float* b2  = (const float*)d_in[6];
    const float* fW1 = (const float*)d_in[7];
    const float* fb1 = (const float*)d_in[8];
    const float* fW2 = (const float*)d_in[9];
    const float* fb2 = (const float*)d_in[10];
    float* out = (float*)d_out;

    int nN = in_sizes[0] / FEAT_IN;
    int nE = in_sizes[1] / 2;
    int nG = out_size;
    const int* src = ei;
    const int* dst = ei + nE;

    int nB   = (nN + BNODES - 1) >> BSH;
    int nCh  = (nE + CH - 1) / CH;
    int nChP = (nCh + 3) & ~3;
    int K    = (nN + 15) / 16;
    int gridC = ((K + 3) / 4) * 8;

    char* w = (char*)d_ws;
    auto alloc = [&](size_t bytes) { char* p = w; w += (bytes + 15) & ~(size_t)15; return p; };
    int*      gHist  = (int*)alloc((size_t)nChP * NBMAX * 4);   // [chunk][bucket]
    int*      gBaseT = (int*)alloc((size_t)NBMAX * nChP * 4);   // [bucket][chunk]
    int*      btot   = (int*)alloc(NBMAX * 4);
    int*      boff   = (int*)alloc((NBMAX + 1) * 4);
    unsigned* EB     = (unsigned*)alloc((size_t)nE * 4);
    int*      rowptr = (int*)alloc((size_t)nN * 4);
    int*      rowend = (int*)alloc((size_t)nN * 4);
    int*      csrP   = (int*)alloc(((size_t)nE + (size_t)NBMAX * PADMAX + 64) * 4);
    float*    dinv   = (float*)alloc((size_t)nN * 4);
    float*    rsb    = (float*)alloc((size_t)nN * 4);
    unsigned* Gc     = (unsigned*)alloc((size_t)2 * (nN + 1) * 16 * 2);
    unsigned* Hc     = (unsigned*)alloc((size_t)2 * (nN + 1) * 16 * 2);
    unsigned* A2b    = (unsigned*)alloc((size_t)(nN + NP2) * 16 * 4);  // bf16 [nN][32]
    float*    psum   = (float*)alloc((size_t)nG * FJ * 4);

    hipMemsetAsync(gHist, 0, (size_t)nChP * NBMAX * 4, stream);
    hipMemsetAsync(psum, 0, (size_t)nG * FJ * 4, stream);

    // CSR build: per-chunk hist -> wave-parallel scan -> atomic-free scatter -> sort
    histPB<<<nCh, 256, 0, stream>>>(dst, gHist, nE, nB);
    scanWB<<<(nB + 3) / 4, 256, 0, stream>>>(gHist, gBaseT, btot, nB, nChP);
    scanOff<<<1, 512, 0, stream>>>(btot, boff, nB);
    scatterEB2<<<nCh, 256, 0, stream>>>(src, dst, gBaseT, boff, EB, nE, nB, nChP);
    bucketSortK<<<nB, 512, 0, stream>>>(EB, boff, rowptr, rowend, csrP, dinv, rsb, nN, nB);

    // layer 1
    gemm1v3<<<(nN + GR - 1) / GR, 256, 0, stream>>>((const float4*)x, W1, dinv, Gc, Hc, nN);
    agg1v2<<<gridC, 256, 0, stream>>>(rowptr, rowend, csrP, Gc, dinv, b1, Hc, nN, K);
    // layer 2
    agg2v2<<<gridC, 256, 0, stream>>>(rowptr, rowend, csrP, Hc, dinv, A2b, nN, K);

    // segmented pooling + MLP (count folded into mlp)
    poolX1<<<(nN + PNPB - 1) / PNPB, 256, 0, stream>>>(Hc, rsb, bat, psum, nN);
    poolX2<<<(nN + NP2 - 1) / NP2, 256, 0, stream>>>(A2b, W2, b2, bat, psum, nN);
    mlp_kernel<<<nG, FH, 0, stream>>>(psum, bat, nN, fW1, fb1, fW2, fb2, out);
}

// Round 18
// 232.322 us; speedup vs baseline: 2.0129x; 1.0226x over previous
//
#include <hip/hip_runtime.h>
#include <stdint.h>

#define FEAT_IN 128
#define F1 32
#define F2 64
#define FJ 96
#define FH 128

#define BSH 8                  // 256 nodes per bucket
#define BNODES 256
#define NBMAX 512
#define CH 4096                // edges per scatter chunk
#define SRCBITS 17             // nN must be < 2^17
#define SRCMASK 0x1FFFFu
#define PADMAX 768             // max pad per bucket (256 nodes * 3)
#define PNPB 256               // nodes per block in poolX1
#define NP2 64                 // nodes per block in poolX2
#define GR 64                  // rows per block in gemm1v3
#define XPAD 132               // padded LDS row stride (floats) for x tile

__device__ __forceinline__ unsigned f2bf(float f) {
    unsigned u = __float_as_uint(f);
    return (u + 0x7FFFu + ((u >> 16) & 1u)) >> 16;   // RNE
}
__device__ __forceinline__ float bf2f_lo(unsigned u) { return __uint_as_float(u << 16); }
__device__ __forceinline__ float bf2f_hi(unsigned u) { return __uint_as_float(u & 0xffff0000u); }
__device__ __forceinline__ void bfacc8(float* a, uint4 v) {
    a[0] += bf2f_lo(v.x); a[1] += bf2f_hi(v.x);
    a[2] += bf2f_lo(v.y); a[3] += bf2f_hi(v.y);
    a[4] += bf2f_lo(v.z); a[5] += bf2f_hi(v.z);
    a[6] += bf2f_lo(v.w); a[7] += bf2f_hi(v.w);
}
__device__ __forceinline__ void fma4(float* acc, float s, float4 wv) {
    acc[0] = fmaf(s, wv.x, acc[0]);
    acc[1] = fmaf(s, wv.y, acc[1]);
    acc[2] = fmaf(s, wv.z, acc[2]);
    acc[3] = fmaf(s, wv.w, acc[3]);
}

// ---------- per-chunk bucket histogram -> gHist[chunk][bucket] (coalesced) ----------
__global__ void __launch_bounds__(512)
histPB(const int* __restrict__ dst, int* __restrict__ gHist, int nE, int nB) {
    __shared__ int h[NBMAX];
    int ck = blockIdx.x, t = threadIdx.x;
    int e0 = ck * CH;
    int ecnt = min(CH, nE - e0);
    if (ecnt <= 0) return;
    for (int i = t; i < nB; i += 512) h[i] = 0;
    __syncthreads();
    for (int i = t; i < ecnt; i += 512) atomicAdd(&h[dst[e0 + i] >> BSH], 1);
    __syncthreads();
    for (int b = t; b < nB; b += 512) gHist[(size_t)ck * NBMAX + b] = h[b];
}

// ---------- wave-per-bucket scan over chunks: bucket-LOCAL bases + totals ----------
__global__ void __launch_bounds__(256)
scanWB(const int* __restrict__ gHist, int* __restrict__ gBaseT,
       int* __restrict__ btot, int nB, int nChP) {
    int wv = blockIdx.x * 4 + (threadIdx.x >> 6);
    if (wv >= nB) return;
    int lane = threadIdx.x & 63;
    int* gp = gBaseT + (size_t)wv * nChP;
    int running = 0;
    for (int c0 = 0; c0 < nChP; c0 += 64) {
        int ck = c0 + lane;
        int v = (ck < nChP) ? gHist[(size_t)ck * NBMAX + wv] : 0;
        int incl = v;
#pragma unroll
        for (int off = 1; off < 64; off <<= 1) {
            int u = __shfl_up(incl, off);
            if (lane >= off) incl += u;
        }
        if (ck < nChP) gp[ck] = running + incl - v;
        running += __shfl(incl, 63);
    }
    if (lane == 0) btot[wv] = running;
}

// ---------- tiny single-block scan of bucket totals -> boff ----------
__global__ void __launch_bounds__(512)
scanOff(const int* __restrict__ btot, int* __restrict__ boff, int nB) {
    __shared__ int ps[512];
    int t = threadIdx.x;
    int v = (t < nB) ? btot[t] : 0;
    ps[t] = v; __syncthreads();
    for (int off = 1; off < 512; off <<= 1) {
        int u = (t >= off) ? ps[t - off] : 0; __syncthreads();
        ps[t] += u; __syncthreads();
    }
    int excl = ps[t] - v;
    if (t < nB) boff[t] = excl;
    if (t == nB - 1) boff[nB] = excl + v;
}

// ---------- scatter edges into buckets (hist from gHist; no re-histogram) ----------
__global__ void __launch_bounds__(512)
scatterEB2(const int* __restrict__ src, const int* __restrict__ dst,
           const int* __restrict__ gHist, const int* __restrict__ gBaseT,
           const int* __restrict__ boff, unsigned* __restrict__ EB,
           int nE, int nB, int nChP) {
    __shared__ int loff[NBMAX], lcur[NBMAX], gbaseL[NBMAX];
    __shared__ int ps[256];
    __shared__ unsigned stagePack[CH];
    __shared__ unsigned short stageBkt[CH];
    int ck = blockIdx.x, t = threadIdx.x;
    int e0 = ck * CH;
    int ecnt = min(CH, nE - e0);
    if (ecnt <= 0) return;
    // pair-scan of this chunk's bucket counts (first 256 threads)
    if (t < 256) {
        int b0 = 2 * t, b1 = 2 * t + 1;
        int c0 = (b0 < nB) ? gHist[(size_t)ck * NBMAX + b0] : 0;
        int c1 = (b1 < nB) ? gHist[(size_t)ck * NBMAX + b1] : 0;
        ps[t] = c0 + c1;
        __syncthreads();
        for (int off = 1; off < 256; off <<= 1) {
            int v = (t >= off) ? ps[t - off] : 0; __syncthreads();
            ps[t] += v; __syncthreads();
        }
        int excl = ps[t] - (c0 + c1);
        if (b0 < nB) { loff[b0] = excl;      lcur[b0] = excl;      gbaseL[b0] = boff[b0] + gBaseT[(size_t)b0 * nChP + ck]; }
        if (b1 < nB) { loff[b1] = excl + c0; lcur[b1] = excl + c0; gbaseL[b1] = boff[b1] + gBaseT[(size_t)b1 * nChP + ck]; }
    } else {
        __syncthreads();
        for (int off = 1; off < 256; off <<= 1) { __syncthreads(); __syncthreads(); }
    }
    __syncthreads();
    for (int i = t; i < ecnt; i += 512) {
        int d = dst[e0 + i], s = src[e0 + i];
        int bkt = d >> BSH;
        int p = atomicAdd(&lcur[bkt], 1);
        stagePack[p] = (unsigned)s | ((unsigned)(d & (BNODES - 1)) << SRCBITS);
        stageBkt[p] = (unsigned short)bkt;
    }
    __syncthreads();
    for (int i = t; i < ecnt; i += 512) {
        int bb = stageBkt[i];
        EB[gbaseL[bb] + (i - loff[bb])] = stagePack[i];
    }
}

// ---------- per-bucket counting sort -> PADDED csr (x4, sentinel nN), dinv, rs ----------
__global__ void __launch_bounds__(512)
bucketSortK(const unsigned* __restrict__ EB, const int* __restrict__ boff,
            int* __restrict__ rowptr, int* __restrict__ rowend, int* __restrict__ csrP,
            float* __restrict__ dinv, float* __restrict__ rs, int nN, int nB) {
    __shared__ int hist[BNODES];
    __shared__ int cur[BNODES];
    __shared__ int ps[256];
    int b = blockIdx.x, t = threadIdx.x;
    int beg = boff[b], end = boff[b + 1];
    if (t < 256) hist[t] = 0;
    __syncthreads();
    for (int i = beg + t; i < end; i += 512) atomicAdd(&hist[EB[i] >> SRCBITS], 1);
    __syncthreads();
    int deg = (t < 256) ? hist[t] : 0;
    int pdeg = (deg + 3) & ~3;
    if (t < 256) ps[t] = pdeg;
    __syncthreads();
    for (int off = 1; off < 256; off <<= 1) {
        int v = (t >= off && t < 256) ? ps[t - off] : 0; __syncthreads();
        if (t < 256) ps[t] += v;
        __syncthreads();
    }
    int base = ((beg + 3) & ~3) + b * PADMAX;
    int excl = 0;
    if (t < 256) {
        excl = base + ps[t] - pdeg;
        int node = (b << BSH) + t;
        if (node < nN) {
            rowptr[node] = excl;
            rowend[node] = excl + pdeg;
            dinv[node] = rsqrtf((float)deg + 1.0f);
            rs[node] = sqrtf((float)deg + 1.0f);
        }
        cur[t] = excl;
    }
    __syncthreads();
    for (int i = beg + t; i < end; i += 512) {
        unsigned v = EB[i];
        int p = atomicAdd(&cur[v >> SRCBITS], 1);
        csrP[p] = (int)(v & SRCMASK);
    }
    __syncthreads();
    if (t < 256) {
        for (int p = cur[t]; p < excl + pdeg; ++p) csrP[p] = nN;
    }
}

// ---------- gemm1 v3: 2x4 register tile, 64 rows/block; block 0 zeroes sentinels ----------
__global__ void __launch_bounds__(256)
gemm1v3(const float4* __restrict__ x4, const float* __restrict__ W1,
        const float* __restrict__ dinv, unsigned* __restrict__ Gc,
        unsigned* __restrict__ Hc, int nN) {
    __shared__ float Ws[FEAT_IN * F1];   // 16 KB
    __shared__ float xs[GR * XPAD];      // 33 KB
    int t = threadIdx.x;
    if (blockIdx.x == 0 && t < 16) {     // zero sentinel rows (node nN), both chunks
        Gc[((size_t)(t >> 3) * (nN + 1) + nN) * 8 + (t & 7)] = 0u;
        Hc[((size_t)(t >> 3) * (nN + 1) + nN) * 8 + (t & 7)] = 0u;
    }
    for (int i = t; i < FEAT_IN * F1; i += 256) Ws[i] = W1[i];
    int rb = blockIdx.x * GR;
    for (int i = t; i < GR * 32; i += 256) {
        int r = i >> 5, c = i & 31;
        int row = rb + r;
        float4 v = (row < nN) ? x4[(size_t)row * 32 + c] : make_float4(0.f, 0.f, 0.f, 0.f);
        *(float4*)(xs + r * XPAD + c * 4) = v;
    }
    __syncthreads();
    int cg = t & 7, rg = t >> 3;
    int r0 = rg * 2, r1 = r0 + 1;
    int j0 = cg * 4;
    float acc0[4] = {0.f, 0.f, 0.f, 0.f};
    float acc1[4] = {0.f, 0.f, 0.f, 0.f};
    const float4* xa4 = (const float4*)(xs + r0 * XPAD);
    const float4* xb4 = (const float4*)(xs + r1 * XPAD);
    const float4* W4 = (const float4*)Ws;
#pragma unroll 4
    for (int kc = 0; kc < 32; ++kc) {
        float4 xa = xa4[kc];
        float4 xb = xb4[kc];
        float4 w0 = W4[(4 * kc + 0) * 8 + cg];
        float4 w1 = W4[(4 * kc + 1) * 8 + cg];
        float4 w2 = W4[(4 * kc + 2) * 8 + cg];
        float4 w3 = W4[(4 * kc + 3) * 8 + cg];
        fma4(acc0, xa.x, w0); fma4(acc0, xa.y, w1);
        fma4(acc0, xa.z, w2); fma4(acc0, xa.w, w3);
        fma4(acc1, xb.x, w0); fma4(acc1, xb.y, w1);
        fma4(acc1, xb.z, w2); fma4(acc1, xb.w, w3);
    }
    int c = j0 >> 4;
    int w = (j0 & 15) >> 1;
    int row0 = rb + r0, row1 = rb + r1;
    if (row0 < nN) {
        float dv = dinv[row0];
        uint2 val;
        val.x = f2bf(acc0[0] * dv) | (f2bf(acc0[1] * dv) << 16);
        val.y = f2bf(acc0[2] * dv) | (f2bf(acc0[3] * dv) << 16);
        *(uint2*)(Gc + ((size_t)c * (nN + 1) + row0) * 8 + w) = val;
    }
    if (row1 < nN) {
        float dv = dinv[row1];
        uint2 val;
        val.x = f2bf(acc1[0] * dv) | (f2bf(acc1[1] * dv) << 16);
        val.y = f2bf(acc1[2] * dv) | (f2bf(acc1[3] * dv) << 16);
        *(uint2*)(Gc + ((size_t)c * (nN + 1) + row1) * 8 + w) = val;
    }
}

// ---------- agg1: ILP-4 gather over chunk, write H chunk (bf16) ----------
__global__ void __launch_bounds__(256)
agg1v2(const int* __restrict__ rowptr, const int* __restrict__ rowend,
       const int* __restrict__ csrP, const unsigned* __restrict__ Gc,
       const float* __restrict__ dinv, const float* __restrict__ b1,
       unsigned* __restrict__ Hc, int nN, int K) {
    int b = blockIdx.x;
    int xcd = b & 7;
    int c = xcd & 1;
    int k = (b >> 3) * 4 + (xcd >> 1);
    if (k >= K) return;
    int t = threadIdx.x, wv = t >> 6, lane = t & 63;
    int node = k * 16 + wv * 4 + (lane >> 4);
    int slot = (lane >> 1) & 7, comp = lane & 1;
    bool vn = node < nN;
    const uint4* Gch = (const uint4*)(Gc + (size_t)c * (nN + 1) * 8);
    float a[8] = {0, 0, 0, 0, 0, 0, 0, 0};
    if (vn) {
        if ((lane & 14) == 0) bfacc8(a, Gch[(size_t)node * 2 + comp]);  // self-loop
        int beg = rowptr[node], endp = rowend[node];
        for (int e = beg + slot * 4; e < endp; e += 32) {
            int4 idx = *(const int4*)(csrP + e);
            uint4 r0 = Gch[(size_t)idx.x * 2 + comp];
            uint4 r1 = Gch[(size_t)idx.y * 2 + comp];
            uint4 r2 = Gch[(size_t)idx.z * 2 + comp];
            uint4 r3 = Gch[(size_t)idx.w * 2 + comp];
            bfacc8(a, r0); bfacc8(a, r1); bfacc8(a, r2); bfacc8(a, r3);
        }
    }
#pragma unroll
    for (int m = 2; m < 16; m <<= 1) {
#pragma unroll
        for (int i = 0; i < 8; ++i) a[i] += __shfl_xor(a[i], m);
    }
    if (vn && (lane & 14) == 0) {
        float dv = dinv[node];
        const float* bb = b1 + c * 16 + comp * 8;
        float h[8];
#pragma unroll
        for (int i = 0; i < 8; ++i) {
            float x1 = fmaxf(fmaf(dv, a[i], bb[i]), 0.f);
            h[i] = dv * x1;
        }
        uint4 hp;
        hp.x = f2bf(h[0]) | (f2bf(h[1]) << 16);
        hp.y = f2bf(h[2]) | (f2bf(h[3]) << 16);
        hp.z = f2bf(h[4]) | (f2bf(h[5]) << 16);
        hp.w = f2bf(h[6]) | (f2bf(h[7]) << 16);
        ((uint4*)(Hc + (size_t)c * (nN + 1) * 8))[(size_t)node * 2 + comp] = hp;
    }
}

// ---------- agg2: ILP-4 gather over H chunk, write A2 bf16 [nN][32] ----------
__global__ void __launch_bounds__(256)
agg2v2(const int* __restrict__ rowptr, const int* __restrict__ rowend,
       const int* __restrict__ csrP, const unsigned* __restrict__ Hc,
       const float* __restrict__ dinv, unsigned* __restrict__ A2b, int nN, int K) {
    int b = blockIdx.x;
    int xcd = b & 7;
    int c = xcd & 1;
    int k = (b >> 3) * 4 + (xcd >> 1);
    if (k >= K) return;
    int t = threadIdx.x, wv = t >> 6, lane = t & 63;
    int node = k * 16 + wv * 4 + (lane >> 4);
    int slot = (lane >> 1) & 7, comp = lane & 1;
    bool vn = node < nN;
    const uint4* Hch = (const uint4*)(Hc + (size_t)c * (nN + 1) * 8);
    float a[8] = {0, 0, 0, 0, 0, 0, 0, 0};
    if (vn) {
        if ((lane & 14) == 0) bfacc8(a, Hch[(size_t)node * 2 + comp]);  // self-loop
        int beg = rowptr[node], endp = rowend[node];
        for (int e = beg + slot * 4; e < endp; e += 32) {
            int4 idx = *(const int4*)(csrP + e);
            uint4 r0 = Hch[(size_t)idx.x * 2 + comp];
            uint4 r1 = Hch[(size_t)idx.y * 2 + comp];
            uint4 r2 = Hch[(size_t)idx.z * 2 + comp];
            uint4 r3 = Hch[(size_t)idx.w * 2 + comp];
            bfacc8(a, r0); bfacc8(a, r1); bfacc8(a, r2); bfacc8(a, r3);
        }
    }
#pragma unroll
    for (int m = 2; m < 16; m <<= 1) {
#pragma unroll
        for (int i = 0; i < 8; ++i) a[i] += __shfl_xor(a[i], m);
    }
    if (vn && (lane & 14) == 0) {
        float dv = dinv[node];
        uint4 o;
        o.x = f2bf(dv * a[0]) | (f2bf(dv * a[1]) << 16);
        o.y = f2bf(dv * a[2]) | (f2bf(dv * a[3]) << 16);
        o.z = f2bf(dv * a[4]) | (f2bf(dv * a[5]) << 16);
        o.w = f2bf(dv * a[6]) | (f2bf(dv * a[7]) << 16);
        ((uint4*)(A2b + (size_t)node * 16))[c * 2 + comp] = o;
    }
}

// ---------- segmented pool of x1 from Hc (batch sorted; flush on graph change) ----------
__global__ void __launch_bounds__(256)
poolX1(const unsigned* __restrict__ Hc, const float* __restrict__ rs,
       const int* __restrict__ batch, float* __restrict__ psum, int nN) {
    int t = threadIdx.x, wv = t >> 6, lane = t & 63;
    int c = wv >> 1, half = wv & 1;
    int base = blockIdx.x * PNPB + half * (PNPB / 2);
    int w32 = lane & 7, noff = lane >> 3;
    const unsigned* Hch = Hc + (size_t)c * (nN + 1) * 8;
    int feat = c * 16 + w32 * 2;
    float a0 = 0.f, a1 = 0.f;
    int curG = -1;
#pragma unroll 4
    for (int i = 0; i < PNPB / 16; ++i) {
        int node = base + noff + 8 * i;
        if (node >= nN) break;
        int bg = batch[node];
        if (bg != curG) {
            if (curG >= 0) {
                atomicAdd(&psum[(size_t)curG * FJ + feat + 0], a0);
                atomicAdd(&psum[(size_t)curG * FJ + feat + 1], a1);
            }
            a0 = a1 = 0.f; curG = bg;
        }
        unsigned v = Hch[(size_t)node * 8 + w32];
        float r = rs[node];
        a0 = fmaf(bf2f_lo(v), r, a0);
        a1 = fmaf(bf2f_hi(v), r, a1);
    }
    if (curG >= 0) {
        atomicAdd(&psum[(size_t)curG * FJ + feat + 0], a0);
        atomicAdd(&psum[(size_t)curG * FJ + feat + 1], a1);
    }
}

// ---------- segmented x2 pool: bf16 A2 LDS-staged, 16 nodes/wave ----------
__global__ void __launch_bounds__(256)
poolX2(const unsigned* __restrict__ A2b, const float* __restrict__ W2,
       const float* __restrict__ b2, const int* __restrict__ batch,
       float* __restrict__ psum, int nN) {
    __shared__ float W2s[F1 * F2];
    __shared__ float aL[NP2][F1];
    int t = threadIdx.x;
    for (int i = t; i < F1 * F2; i += 256) W2s[i] = W2[i];
    int nbase = blockIdx.x * NP2;
    {
        const uint4* A4 = (const uint4*)(A2b + (size_t)nbase * 16);
        for (int i = t; i < NP2 * 4; i += 256) {
            int gnode = nbase + (i >> 2);
            uint4 v = (gnode < nN) ? A4[i] : make_uint4(0u, 0u, 0u, 0u);
            float* d = aL[i >> 2] + (i & 3) * 8;
            d[0] = bf2f_lo(v.x); d[1] = bf2f_hi(v.x);
            d[2] = bf2f_lo(v.y); d[3] = bf2f_hi(v.y);
            d[4] = bf2f_lo(v.z); d[5] = bf2f_hi(v.z);
            d[6] = bf2f_lo(v.w); d[7] = bf2f_hi(v.w);
        }
    }
    __syncthreads();
    int wv = t >> 6, lane = t & 63;
    int n0 = wv * (NP2 / 4);
    float bj = b2[lane];
    float acc = 0.f;
    int curG = -1;
    for (int i = 0; i < NP2 / 4; ++i) {
        int node = nbase + n0 + i;
        if (node >= nN) break;
        int bg = batch[node];
        if (bg != curG) {
            if (curG >= 0) atomicAdd(&psum[(size_t)curG * FJ + F1 + lane], acc);
            acc = 0.f; curG = bg;
        }
        const float* a = aL[n0 + i];
        float dot = 0.f;
#pragma unroll
        for (int k = 0; k < F1; ++k) dot = fmaf(a[k], W2s[k * F2 + lane], dot);
        acc += fmaxf(dot + bj, 0.f);
    }
    if (curG >= 0) atomicAdd(&psum[(size_t)curG * FJ + F1 + lane], acc);
}

// ---------- final MLP; per-block count via binary search ----------
__global__ void mlp_kernel(const float* __restrict__ psum, const int* __restrict__ batch,
                           int nN,
                           const float* __restrict__ fW1, const float* __restrict__ fb1,
                           const float* __restrict__ fW2, const float* __restrict__ fb2,
                           float* __restrict__ out) {
    __shared__ float p[FJ];
    __shared__ float red[FH];
    __shared__ float cinv;
    int g = blockIdx.x, tid = threadIdx.x;
    if (tid == 0) {
        int lo = 0, hi = nN;
        while (lo < hi) { int m = (lo + hi) >> 1; if (batch[m] < g) lo = m + 1; else hi = m; }
        int s = lo;
        lo = 0; hi = nN;
        while (lo < hi) { int m = (lo + hi) >> 1; if (batch[m] < g + 1) lo = m + 1; else hi = m; }
        cinv = 1.0f / fmaxf((float)(lo - s), 1.0f);
    }
    __syncthreads();
    if (tid < FJ) p[tid] = psum[g * FJ + tid] * cinv;
    __syncthreads();
    float acc = fb1[tid];
    for (int k = 0; k < FJ; ++k) acc = fmaf(p[k], fW1[k * FH + tid], acc);
    float h = fmaxf(acc, 0.f);
    red[tid] = h * fW2[tid];
    __syncthreads();
    for (int s = FH / 2; s > 0; s >>= 1) {
        if (tid < s) red[tid] += red[tid + s];
        __syncthreads();
    }
    if (tid == 0) out[g] = red[0] + fb2[0];
}

extern "C" void kernel_launch(void* const* d_in, const int* in_sizes, int n_in,
                              void* d_out, int out_size, void* d_ws, size_t ws_size,
                              hipStream_t stream) {
    const float* x   = (const float*)d_in[0];
    const int*   ei  = (const int*)d_in[1];
    const int*   bat = (const int*)d_in[2];
    const float* W1  = (const float*)d_in[3];
    const float* b1  = (const float*)d_in[4];
    const float* W2  = (const float*)d_in[5];
    const float* b2  = (const float*)d_in[6];
    const float* fW1 = (const float*)d_in[7];
    const float* fb1 = (const float*)d_in[8];
    const float* fW2 = (const float*)d_in[9];
    const float* fb2 = (const float*)d_in[10];
    float* out = (float*)d_out;

    int nN = in_sizes[0] / FEAT_IN;
    int nE = in_sizes[1] / 2;
    int nG = out_size;
    const int* src = ei;
    const int* dst = ei + nE;

    int nB   = (nN + BNODES - 1) >> BSH;
    int nCh  = (nE + CH - 1) / CH;
    int nChP = (nCh + 3) & ~3;
    int K    = (nN + 15) / 16;
    int gridC = ((K + 3) / 4) * 8;

    char* w = (char*)d_ws;
    auto alloc = [&](size_t bytes) { char* p = w; w += (bytes + 15) & ~(size_t)15; return p; };
    int*      gHist  = (int*)alloc((size_t)nChP * NBMAX * 4);   // [chunk][bucket]
    int*      gBaseT = (int*)alloc((size_t)NBMAX * nChP * 4);   // [bucket][chunk]
    int*      btot   = (int*)alloc(NBMAX * 4);
    int*      boff   = (int*)alloc((NBMAX + 1) * 4);
    unsigned* EB     = (unsigned*)alloc((size_t)nE * 4);
    int*      rowptr = (int*)alloc((size_t)nN * 4);
    int*      rowend = (int*)alloc((size_t)nN * 4);
    int*      csrP   = (int*)alloc(((size_t)nE + (size_t)NBMAX * PADMAX + 64) * 4);
    float*    dinv   = (float*)alloc((size_t)nN * 4);
    float*    rsb    = (float*)alloc((size_t)nN * 4);
    unsigned* Gc     = (unsigned*)alloc((size_t)2 * (nN + 1) * 16 * 2);
    unsigned* Hc     = (unsigned*)alloc((size_t)2 * (nN + 1) * 16 * 2);
    unsigned* A2b    = (unsigned*)alloc((size_t)(nN + NP2) * 16 * 4);
    float*    psum   = (float*)alloc((size_t)nG * FJ * 4);

    hipMemsetAsync(gHist, 0, (size_t)nChP * NBMAX * 4, stream);
    hipMemsetAsync(psum, 0, (size_t)nG * FJ * 4, stream);

    // CSR build
    histPB<<<nCh, 512, 0, stream>>>(dst, gHist, nE, nB);
    scanWB<<<(nB + 3) / 4, 256, 0, stream>>>(gHist, gBaseT, btot, nB, nChP);
    scanOff<<<1, 512, 0, stream>>>(btot, boff, nB);
    scatterEB2<<<nCh, 512, 0, stream>>>(src, dst, gHist, gBaseT, boff, EB, nE, nB, nChP);
    bucketSortK<<<nB, 512, 0, stream>>>(EB, boff, rowptr, rowend, csrP, dinv, rsb, nN, nB);

    // layer 1
    gemm1v3<<<(nN + GR - 1) / GR, 256, 0, stream>>>((const float4*)x, W1, dinv, Gc, Hc, nN);
    agg1v2<<<gridC, 256, 0, stream>>>(rowptr, rowend, csrP, Gc, dinv, b1, Hc, nN, K);
    // layer 2
    agg2v2<<<gridC, 256, 0, stream>>>(rowptr, rowend, csrP, Hc, dinv, A2b, nN, K);

    // segmented pooling + MLP
    poolX1<<<(nN + PNPB - 1) / PNPB, 256, 0, stream>>>(Hc, rsb, bat, psum, nN);
    poolX2<<<(nN + NP2 - 1) / NP2, 256, 0, stream>>>(A2b, W2, b2, bat, psum, nN);
    mlp_kernel<<<nG, FH, 0, stream>>>(psum, bat, nN, fW1, fb1, fW2, fb2, out);
}